// Round 11
// baseline (562.006 us; speedup 1.0000x reference)
//
#include <hip/hip_runtime.h>
#include <math.h>

#define NB 8
#define NH 8
#define NT 1024
#define DMODEL 512

typedef short bh8 __attribute__((ext_vector_type(8)));   // 8 bf16 (4 VGPRs)
typedef float fx4 __attribute__((ext_vector_type(4)));   // MFMA accumulator

__device__ __forceinline__ unsigned short f2bf(float f) {
  union { float f; unsigned int u; } v; v.f = f;
  unsigned int u = v.u + 0x7FFFu + ((v.u >> 16) & 1u);
  return (unsigned short)(u >> 16);
}
__device__ __forceinline__ float bf2f(unsigned short h) {
  union { unsigned int u; float f; } v; v.u = ((unsigned int)h) << 16;
  return v.f;
}

// ---------------- prep: weights -> masked bf16 (cm for gemm B), zero pad chunks ----------------
__global__ __launch_bounds__(256) void k_prep(
    const float* __restrict__ Wq, const float* __restrict__ Wk,
    const float* __restrict__ Wv, const float* __restrict__ WO,
    const int* __restrict__ g,
    const float* __restrict__ Wqa, const float* __restrict__ Wka,
    const float* __restrict__ Wqp, const float* __restrict__ Wkp,
    unsigned short* __restrict__ Wqkvcm, unsigned short* __restrict__ WO_mb,
    unsigned short* __restrict__ Wacm, unsigned short* __restrict__ Wpcm,
    unsigned short* __restrict__ qcf, unsigned short* __restrict__ kcf)
{
  int stride = gridDim.x * 256;
  int tid0 = blockIdx.x * 256 + threadIdx.x;
  for (int i = tid0; i < 1536 * 512; i += stride) {
    int m = i & 511;
    int j = i >> 9;
    int k = j & 63;
    int hh = (j >> 6) & 7;
    int qkv = j >> 9;
    const float* W = (qkv == 0) ? Wq : (qkv == 1 ? Wk : Wv);
    float val = W[(hh * 64 + k) * 512 + m] * (float)g[k * 64 + (m & 63)];
    Wqkvcm[((size_t)(m >> 3) * 1536 + j) * 8 + (m & 7)] = f2bf(val);
  }
  for (int i = tid0; i < 512 * 512; i += stride) {
    int d = i & 511, e = i >> 9;
    WO_mb[i] = f2bf(WO[i] * (float)g[(e & 63) * 64 + (d & 63)]);
  }
  for (int i = tid0; i < 512 * 256; i += stride) {
    int a = i & 255, j = i >> 8;
    float val = (j < 256) ? Wqa[j * 256 + a] : Wka[(j - 256) * 256 + a];
    Wacm[((size_t)(a >> 3) * 512 + j) * 8 + (a & 7)] = f2bf(val);
  }
  for (int i = tid0; i < 256 * 128; i += stride) {
    int p = i & 127, j = i >> 7;
    float val = (j < 128) ? Wqp[j * 128 + p] : Wkp[(j - 128) * 128 + p];
    Wpcm[((size_t)(p >> 3) * 256 + j) * 8 + (p & 7)] = f2bf(val);
  }
  for (int i = tid0; i < 64 * 16384; i += stride) {
    int bh = i >> 14, rest = i & 16383;
    size_t addr = (size_t)(bh * 8 + 6) * 8192 + rest;
    qcf[addr] = 0; kcf[addr] = 0;
  }
}

// ---------------- f32 row-major [M][K] -> bf16 chunk-major [K/8][M][8] ----------------
__global__ __launch_bounds__(256) void k_tocm(
    const float* __restrict__ src, unsigned short* __restrict__ dst, int M, int K)
{
  __shared__ unsigned short t16[64][80];
  const int bm = blockIdx.x * 64, bk = blockIdx.y * 64;
  const int tid = threadIdx.x;
  {
    int r = tid >> 2, q = tid & 3;
    const float* sp = src + (size_t)(bm + r) * K + bk + q * 16;
#pragma unroll
    for (int j = 0; j < 4; ++j) {
      float4 v = *(const float4*)(sp + j * 4);
      t16[r][q * 16 + j * 4 + 0] = f2bf(v.x);
      t16[r][q * 16 + j * 4 + 1] = f2bf(v.y);
      t16[r][q * 16 + j * 4 + 2] = f2bf(v.z);
      t16[r][q * 16 + j * 4 + 3] = f2bf(v.w);
    }
  }
  __syncthreads();
  {
    int cq = tid >> 5, rr = tid & 31;
#pragma unroll
    for (int h = 0; h < 2; ++h) {
      int r2 = rr + h * 32;
      unsigned short* dp = dst + ((size_t)((bk >> 3) + cq) * M + bm + r2) * 8;
      *(int4*)dp = *(const int4*)&t16[r2][cq * 8];
    }
  }
}

// ---------------- fused QKV gemm ----------------
__global__ __launch_bounds__(256) void k_gqkv(
    const unsigned short* __restrict__ Acm, const unsigned short* __restrict__ Bcm,
    const float* __restrict__ bq, const float* __restrict__ bk, const float* __restrict__ bv,
    const float* __restrict__ w,
    unsigned short* __restrict__ Qf, unsigned short* __restrict__ Kf,
    unsigned short* __restrict__ Vrow)
{
  const int M = 8192, N = 1536, K = 512;
  const int bm = blockIdx.y * 128, bn = blockIdx.x * 128;
  const int tid = threadIdx.x, lane = tid & 63, wv = tid >> 6;
  const int wr = wv >> 1, wc = wv & 1;
  const int lrow = lane & 15, lgrp = lane >> 4;
  fx4 acc[4][4];
#pragma unroll
  for (int m = 0; m < 4; ++m)
#pragma unroll
    for (int n = 0; n < 4; ++n) acc[m][n] = (fx4){0.f, 0.f, 0.f, 0.f};
  for (int k0 = 0; k0 < K; k0 += 32) {
    bh8 af[4], bf[4];
#pragma unroll
    for (int m = 0; m < 4; ++m)
      af[m] = *(const bh8*)(Acm + (((size_t)((k0 >> 3) + lgrp)) * M + bm + wr * 64 + m * 16 + lrow) * 8);
#pragma unroll
    for (int n = 0; n < 4; ++n)
      bf[n] = *(const bh8*)(Bcm + (((size_t)((k0 >> 3) + lgrp)) * N + bn + wc * 64 + n * 16 + lrow) * 8);
#pragma unroll
    for (int m = 0; m < 4; ++m)
#pragma unroll
      for (int n = 0; n < 4; ++n)
        acc[m][n] = __builtin_amdgcn_mfma_f32_16x16x32_bf16(af[m], bf[n], acc[m][n], 0, 0, 0);
  }
  const int qkv = bn >> 9;
  const int hh = ((bn + wc * 64) >> 6) & 7;
  const float w0 = w[0];
  const float* bias = (qkv == 0) ? bq : (qkv == 1 ? bk : bv);
  float bvals[4];
#pragma unroll
  for (int n = 0; n < 4; ++n) bvals[n] = bias[hh * 64 + n * 16 + lrow];
#pragma unroll
  for (int m = 0; m < 4; ++m)
#pragma unroll
    for (int r = 0; r < 4; ++r) {
      int row = bm + wr * 64 + m * 16 + lgrp * 4 + r;
      int b = row >> 10, t = row & 1023;
      int bh = b * 8 + hh;
      float v0 = acc[m][0][r] + bvals[0];
      float v1 = acc[m][1][r] + bvals[1];
      float v2 = acc[m][2][r] + bvals[2];
      float v3 = acc[m][3][r] + bvals[3];
      if (qkv < 2) {
        float p = v0 * v0 + v1 * v1 + v2 * v2 + v3 * v3;
        p += __shfl_xor(p, 1); p += __shfl_xor(p, 2);
        p += __shfl_xor(p, 4); p += __shfl_xor(p, 8);
        float rn = 1.0f / fmaxf(sqrtf(p), 1e-12f);
        if (qkv == 0) rn *= w0;
        unsigned short* dst = (qkv == 0) ? Qf : Kf;
        size_t base = (size_t)bh * 65536 + (size_t)(lrow >> 3) * 8192 + (size_t)t * 8 + (lrow & 7);
        dst[base + 0 * 16384] = f2bf(v0 * rn);
        dst[base + 1 * 16384] = f2bf(v1 * rn);
        dst[base + 2 * 16384] = f2bf(v2 * rn);
        dst[base + 3 * 16384] = f2bf(v3 * rn);
      } else {
        size_t vb = ((size_t)bh * NT + t) * 64 + lrow;
        Vrow[vb + 0]  = f2bf(v0);
        Vrow[vb + 16] = f2bf(v1);
        Vrow[vb + 32] = f2bf(v2);
        Vrow[vb + 48] = f2bf(v3);
      }
    }
}

// ---------------- fused aux gemm ----------------
__global__ __launch_bounds__(256) void k_gaux(
    const unsigned short* __restrict__ Acm, const unsigned short* __restrict__ Bcm,
    const float* __restrict__ bqa, const float* __restrict__ bka,
    const float* __restrict__ wa,
    unsigned short* __restrict__ qcf, unsigned short* __restrict__ kcf)
{
  const int M = 8192, N = 512, K = 256;
  const int bm = blockIdx.y * 128, bn = blockIdx.x * 128;
  const int tid = threadIdx.x, lane = tid & 63, wv = tid >> 6;
  const int wr = wv >> 1, wc = wv & 1;
  const int lrow = lane & 15, lgrp = lane >> 4;
  fx4 acc[4][4];
#pragma unroll
  for (int m = 0; m < 4; ++m)
#pragma unroll
    for (int n = 0; n < 4; ++n) acc[m][n] = (fx4){0.f, 0.f, 0.f, 0.f};
  for (int k0 = 0; k0 < K; k0 += 32) {
    bh8 af[4], bf[4];
#pragma unroll
    for (int m = 0; m < 4; ++m)
      af[m] = *(const bh8*)(Acm + (((size_t)((k0 >> 3) + lgrp)) * M + bm + wr * 64 + m * 16 + lrow) * 8);
#pragma unroll
    for (int n = 0; n < 4; ++n)
      bf[n] = *(const bh8*)(Bcm + (((size_t)((k0 >> 3) + lgrp)) * N + bn + wc * 64 + n * 16 + lrow) * 8);
#pragma unroll
    for (int m = 0; m < 4; ++m)
#pragma unroll
      for (int n = 0; n < 4; ++n)
        acc[m][n] = __builtin_amdgcn_mfma_f32_16x16x32_bf16(af[m], bf[n], acc[m][n], 0, 0, 0);
  }
  const int isK = (bn >> 8) & 1;
  const int hh0 = (((bn & 255) + wc * 64) >> 5) & 7;
  const float wa0 = wa[0];
  const float* bias = isK ? bka : bqa;
  float bvals[4];
#pragma unroll
  for (int n = 0; n < 4; ++n) bvals[n] = bias[(hh0 + (n >> 1)) * 32 + (n & 1) * 16 + lrow];
  unsigned short* dst = isK ? kcf : qcf;
  const float scale = isK ? 1.0f : wa0;
#pragma unroll
  for (int m = 0; m < 4; ++m)
#pragma unroll
    for (int r = 0; r < 4; ++r) {
      int row = bm + wr * 64 + m * 16 + lgrp * 4 + r;
      int b = row >> 10, t = row & 1023;
      float v0 = acc[m][0][r] + bvals[0];
      float v1 = acc[m][1][r] + bvals[1];
      float v2 = acc[m][2][r] + bvals[2];
      float v3 = acc[m][3][r] + bvals[3];
      float plo = v0 * v0 + v1 * v1;
      float phi = v2 * v2 + v3 * v3;
      plo += __shfl_xor(plo, 1); plo += __shfl_xor(plo, 2);
      plo += __shfl_xor(plo, 4); plo += __shfl_xor(plo, 8);
      phi += __shfl_xor(phi, 1); phi += __shfl_xor(phi, 2);
      phi += __shfl_xor(phi, 4); phi += __shfl_xor(phi, 8);
      float rlo = scale / fmaxf(sqrtf(plo), 1e-12f);
      float rhi = scale / fmaxf(sqrtf(phi), 1e-12f);
      size_t b0 = (size_t)(b * 8 + hh0) * 65536 + (size_t)(lrow >> 3) * 8192 + (size_t)t * 8 + (lrow & 7);
      size_t b1 = (size_t)(b * 8 + hh0 + 1) * 65536 + (size_t)(lrow >> 3) * 8192 + (size_t)t * 8 + (lrow & 7);
      dst[b0 + 0]     = f2bf(v0 * rlo);
      dst[b0 + 16384] = f2bf(v1 * rlo);
      dst[b1 + 0]     = f2bf(v2 * rhi);
      dst[b1 + 16384] = f2bf(v3 * rhi);
    }
}

// ---------------- fused pos gemm ----------------
__global__ __launch_bounds__(256) void k_gpos(
    const unsigned short* __restrict__ Acm, const unsigned short* __restrict__ Bcm,
    const float* __restrict__ bqp, const float* __restrict__ bkp,
    const float* __restrict__ wp,
    unsigned short* __restrict__ qcf, unsigned short* __restrict__ kcf)
{
  const int M = 8192, N = 256, K = 128;
  const int bm = blockIdx.y * 128, bn = blockIdx.x * 128;
  const int tid = threadIdx.x, lane = tid & 63, wv = tid >> 6;
  const int wr = wv >> 1, wc = wv & 1;
  const int lrow = lane & 15, lgrp = lane >> 4;
  fx4 acc[4][4];
#pragma unroll
  for (int m = 0; m < 4; ++m)
#pragma unroll
    for (int n = 0; n < 4; ++n) acc[m][n] = (fx4){0.f, 0.f, 0.f, 0.f};
  for (int k0 = 0; k0 < K; k0 += 32) {
    bh8 af[4], bf[4];
#pragma unroll
    for (int m = 0; m < 4; ++m)
      af[m] = *(const bh8*)(Acm + (((size_t)((k0 >> 3) + lgrp)) * M + bm + wr * 64 + m * 16 + lrow) * 8);
#pragma unroll
    for (int n = 0; n < 4; ++n)
      bf[n] = *(const bh8*)(Bcm + (((size_t)((k0 >> 3) + lgrp)) * N + bn + wc * 64 + n * 16 + lrow) * 8);
#pragma unroll
    for (int m = 0; m < 4; ++m)
#pragma unroll
      for (int n = 0; n < 4; ++n)
        acc[m][n] = __builtin_amdgcn_mfma_f32_16x16x32_bf16(af[m], bf[n], acc[m][n], 0, 0, 0);
  }
  const int isK = (bn >> 7) & 1;
  const int bh0 = (((bn & 127) + wc * 64) >> 4) & 7;
  const float wp0 = wp[0];
  const float* bias = isK ? bkp : bqp;
  float bvals[4];
#pragma unroll
  for (int n = 0; n < 4; ++n) bvals[n] = bias[(bh0 + n) * 16 + lrow];
  unsigned short* dst = isK ? kcf : qcf;
  const float scale = isK ? 1.0f : wp0;
#pragma unroll
  for (int m = 0; m < 4; ++m)
#pragma unroll
    for (int r = 0; r < 4; ++r) {
      int row = bm + wr * 64 + m * 16 + lgrp * 4 + r;
      int b = row >> 10, t = row & 1023;
      float v[4];
      v[0] = acc[m][0][r] + bvals[0];
      v[1] = acc[m][1][r] + bvals[1];
      v[2] = acc[m][2][r] + bvals[2];
      v[3] = acc[m][3][r] + bvals[3];
#pragma unroll
      for (int n = 0; n < 4; ++n) {
        float p = v[n] * v[n];
        p += __shfl_xor(p, 1); p += __shfl_xor(p, 2);
        p += __shfl_xor(p, 4); p += __shfl_xor(p, 8);
        float rn = scale / fmaxf(sqrtf(p), 1e-12f);
        size_t addr = (size_t)(b * 8 + bh0 + n) * 65536 + (size_t)(4 + (lrow >> 3)) * 8192
                    + (size_t)t * 8 + (lrow & 7);
        dst[addr] = f2bf(v[n] * rn);
      }
    }
}

// ---------------- V transpose ----------------
__global__ __launch_bounds__(256) void k_vtr(
    const unsigned short* __restrict__ Vrow, unsigned short* __restrict__ Vc)
{
  __shared__ unsigned short tile[64][72];
  const int tt = blockIdx.x, bh = blockIdx.y;
  const int tid = threadIdx.x;
  const int r = tid & 63, g = tid >> 6;
  const unsigned short* src = Vrow + ((size_t)bh * NT + tt * 64 + r) * 64 + g * 16;
  int4 v0 = *(const int4*)(src);
  int4 v1 = *(const int4*)(src + 8);
  const unsigned short* pv0 = (const unsigned short*)&v0;
  const unsigned short* pv1 = (const unsigned short*)&v1;
#pragma unroll
  for (int j = 0; j < 8; ++j) tile[g * 16 + j][r] = pv0[j];
#pragma unroll
  for (int j = 0; j < 8; ++j) tile[g * 16 + 8 + j][r] = pv1[j];
  __syncthreads();
  unsigned short* dst0 = Vc + ((size_t)(bh * 128 + tt * 8 + g * 2) * 64 + r) * 8;
  unsigned short* dst1 = Vc + ((size_t)(bh * 128 + tt * 8 + g * 2 + 1) * 64 + r) * 8;
  *(int4*)dst0 = *(const int4*)&tile[r][g * 16];
  *(int4*)(dst1) = *(const int4*)&tile[r][g * 16 + 8];
}

// ---------------- slide body (EDGE: full cnt; else cnt==17) ----------------
template<bool EDGE, bool PBM>
__device__ __forceinline__ void slide_body(
    const float (*Se)[81], const unsigned short (*Pd)[66],
    int a0, int c0, int b, int hh, int wv, int lane, int base_cl,
    float* lacc, float* __restrict__ attn, unsigned short* __restrict__ PB)
{
  float dval = 0.f;
  {
    int rr = wv * 16 + (lane & 15);
#pragma unroll
    for (int u = 0; u <= 16; ++u) dval += Se[rr + u][u];
  }
  float num = 0.f;
#pragma unroll
  for (int s = 0; s < 16; ++s) {
    int a_l = wv * 16 + s;
    int c_l = (base_cl + s) & 63;
    if (s == 0) {
      num = 0.f;
#pragma unroll
      for (int u = 0; u <= 16; ++u) num += Se[a_l + u][c_l + u];
    } else {
      int cm1 = (c_l == 0) ? 0 : (c_l - 1);
      float up = Se[a_l + 16][c_l + 16] - Se[a_l - 1][cm1];
      float dS = __shfl(dval, s);
      num = (c_l == 0) ? dS : (num + up);
    }
    int a = a0 + a_l, c = c0 + c_l;
    float sim;
    if (EDGE) {
      int mn = min(a, c), mx = max(a, c);
      float cntf = (float)(min(8, mn) + min(8, 1023 - mx) + 1);
      sim = num * __builtin_amdgcn_rcpf(cntf) + bf2f(Pd[a_l][c_l]);
    } else {
      sim = num * (1.0f / 17.0f) + bf2f(Pd[a_l][c_l]);
    }
    float pe = __expf(sim);
    lacc[s] += pe;
    size_t oidx = (((size_t)(b * NT + a)) * NH + hh) * NT + c;
    if (PBM) PB[oidx] = f2bf(pe);
    else     attn[oidx] = pe;
  }
}

// ---------------- sim kernel: ctg=2, XCD-swizzled, chunk-major frags ----------------
// grid 2048 flat. wgid = (flat&7)*256 + flat>>3. bh=wgid>>5, ctg=(wgid>>4)&1, at=wgid&15
// __launch_bounds__(256,4): cap total VGPR+AGPR at 128/wave -> 4 waves/SIMD (was ~2: 120 VGPR
// + hidden AGPR pushed past 128 -> Occupancy 22%).
template<bool PBM>
__global__ __launch_bounds__(256, 4) void k_sim(
    const unsigned short* __restrict__ Qf, const unsigned short* __restrict__ Kf,
    const unsigned short* __restrict__ qcf, const unsigned short* __restrict__ kcf,
    float* __restrict__ lsumP, float* __restrict__ attn, unsigned short* __restrict__ PB)
{
  __shared__ float Se[80][81];
  __shared__ unsigned short Pd[64][66];
  const int flat = blockIdx.x;
  const int wgid = (flat & 7) * 256 + (flat >> 3);
  const int bh = wgid >> 5;
  const int ctg = (wgid >> 4) & 1;
  const int at = wgid & 15;
  const int a0 = at * 64;
  const int b = bh >> 3, hh = bh & 7;
  const int tid = threadIdx.x;
  const int lane = tid & 63, wv = tid >> 6;
  const int lrow16 = lane & 15, lgrp = lane >> 4;
  const bh8 zfrag = {0, 0, 0, 0, 0, 0, 0, 0};
  const int base_cl = (wv * 16 + lane) & 63;
  float lacc[16];
#pragma unroll
  for (int s = 0; s < 16; ++s) lacc[s] = 0.f;

  const unsigned short* Qc = Qf + (size_t)(bh * 8 + lgrp) * NT * 8;
  const unsigned short* Kc = Kf + (size_t)(bh * 8 + lgrp) * NT * 8;

  bh8 qa0, qa1;
  {
    const unsigned short* qb = qcf + ((size_t)(bh * 8 + lgrp) * NT + a0 + wv * 16 + lrow16) * 8;
    qa0 = *(const bh8*)(qb);
    qa1 = *(const bh8*)(qb + (size_t)4 * NT * 8);
  }

  for (int ct = ctg * 8; ct < ctg * 8 + 8; ++ct) {
    const int c0 = ct * 64;
    __syncthreads();

#pragma unroll
    for (int i = 0; i < 7; ++i) {
      int tt = wv + 4 * i;
      if (tt < 25) {
        int tr = tt / 5, tc = tt % 5;
        int ar = a0 - 8 + tr * 16 + lrow16;
        int kr = c0 - 8 + tc * 16 + lrow16;
        bool av = (unsigned)ar < (unsigned)NT;
        bool bv = (unsigned)kr < (unsigned)NT;
        const unsigned short* ap = Qc + (size_t)(av ? ar : 0) * 8;
        const unsigned short* bp = Kc + (size_t)(bv ? kr : 0) * 8;
        bh8 af0 = av ? *(const bh8*)(ap) : zfrag;
        bh8 af1 = av ? *(const bh8*)(ap + (size_t)4 * NT * 8) : zfrag;
        bh8 bf0 = bv ? *(const bh8*)(bp) : zfrag;
        bh8 bf1 = bv ? *(const bh8*)(bp + (size_t)4 * NT * 8) : zfrag;
        fx4 acc = {0.f, 0.f, 0.f, 0.f};
        acc = __builtin_amdgcn_mfma_f32_16x16x32_bf16(af0, bf0, acc, 0, 0, 0);
        acc = __builtin_amdgcn_mfma_f32_16x16x32_bf16(af1, bf1, acc, 0, 0, 0);
#pragma unroll
        for (int r = 0; r < 4; ++r)
          Se[tr * 16 + lgrp * 4 + r][tc * 16 + lrow16] = acc[r];
      }
    }

#pragma unroll
    for (int n = 0; n < 4; ++n) {
      const unsigned short* kb = kcf + ((size_t)(bh * 8 + lgrp) * NT + c0 + n * 16 + lrow16) * 8;
      bh8 kb0 = *(const bh8*)(kb);
      bh8 kb1 = *(const bh8*)(kb + (size_t)4 * NT * 8);
      fx4 pacc = {0.f, 0.f, 0.f, 0.f};
      pacc = __builtin_amdgcn_mfma_f32_16x16x32_bf16(qa0, kb0, pacc, 0, 0, 0);
      pacc = __builtin_amdgcn_mfma_f32_16x16x32_bf16(qa1, kb1, pacc, 0, 0, 0);
#pragma unroll
      for (int r = 0; r < 4; ++r)
        Pd[wv * 16 + lgrp * 4 + r][n * 16 + lrow16] = f2bf(pacc[r]);
    }

    __syncthreads();

    bool edge = (ct == 0) || (ct == 15) || (at == 0) || (at == 15);
    if (edge)
      slide_body<true, PBM>(Se, Pd, a0, c0, b, hh, wv, lane, base_cl, lacc, attn, PB);
    else
      slide_body<false, PBM>(Se, Pd, a0, c0, b, hh, wv, lane, base_cl, lacc, attn, PB);
  }

#pragma unroll
  for (int s = 0; s < 16; ++s) {
    float v = lacc[s];
#pragma unroll
    for (int off = 32; off; off >>= 1) v += __shfl_xor(v, off);
    if (lane == 0)
      lsumP[(size_t)ctg * 65536 + (size_t)bh * NT + a0 + wv * 16 + s] = v;
  }
}

// ---------------- normalize attn + PV via MFMA ----------------
template<bool PBM>
__global__ __launch_bounds__(256) void k_pv(
    const unsigned short* __restrict__ Vc, const float* __restrict__ lsumP,
    float* __restrict__ attn, const unsigned short* __restrict__ PB,
    float* __restrict__ deta, unsigned short* __restrict__ detab)
{
  const int at = blockIdx.x, bh = blockIdx.y;
  const int a0 = at * 64;
  const int b = bh >> 3, hh = bh & 7;
  const int tid = threadIdx.x, lane = tid & 63, wv = tid >> 6;
  const int lrow = lane & 15, lgrp = lane >> 4;
  const int arow = a0 + wv * 16 + lrow;
  const size_t lidx = (size_t)bh * NT + arow;
  const float rl = 1.0f / (lsumP[lidx] + lsumP[65536 + lidx]);
  fx4 acc0 = {0.f,0.f,0.f,0.f}, acc1 = {0.f,0.f,0.f,0.f};
  fx4 acc2 = {0.f,0.f,0.f,0.f}, acc3 = {0.f,0.f,0.f,0.f};
  float* arowp = attn + (((size_t)(b * NT + arow)) * NH + hh) * NT;
  const unsigned short* pbrow = PBM ? (PB + (((size_t)(b * NT + arow)) * NH + hh) * NT) : nullptr;
  for (int ct = 0; ct < 16; ++ct) {
    const int c0 = ct * 64;
#pragma unroll
    for (int kh = 0; kh < 2; ++kh) {
      bh8 af;
      if (PBM) {
        af = *(const bh8*)(pbrow + c0 + kh * 32 + lgrp * 8);
        const unsigned short* ap = (const unsigned short*)&af;
        float4 o0, o1;
        o0.x = bf2f(ap[0]) * rl; o0.y = bf2f(ap[1]) * rl;
        o0.z = bf2f(ap[2]) * rl; o0.w = bf2f(ap[3]) * rl;
        o1.x = bf2f(ap[4]) * rl; o1.y = bf2f(ap[5]) * rl;
        o1.z = bf2f(ap[6]) * rl; o1.w = bf2f(ap[7]) * rl;
        *(float4*)(arowp + c0 + kh * 32 + lgrp * 8) = o0;
        *(float4*)(arowp + c0 + kh * 32 + lgrp * 8 + 4) = o1;
      } else {
        float* pp = arowp + c0 + kh * 32 + lgrp * 8;
        float4 p0 = *(float4*)pp;
        float4 p1 = *(float4*)(pp + 4);
        p0.x *= rl; p0.y *= rl; p0.z *= rl; p0.w *= rl;
        p1.x *= rl; p1.y *= rl; p1.z *= rl; p1.w *= rl;
        *(float4*)pp = p0;
        *(float4*)(pp + 4) = p1;
        unsigned short* afp = (unsigned short*)&af;
        afp[0] = f2bf(p0.x); afp[1] = f2bf(p0.y); afp[2] = f2bf(p0.z); afp[3] = f2bf(p0.w);
        afp[4] = f2bf(p1.x); afp[5] = f2bf(p1.y); afp[6] = f2bf(p1.z); afp[7] = f2bf(p1.w);
      }
      const unsigned short* vk = Vc + ((size_t)(bh * 128 + (c0 >> 3) + kh * 4 + lgrp) * 64 + lrow) * 8;
      acc0 = __builtin_amdgcn_mfma_f32_16x16x32_bf16(af, *(const bh8*)(vk + 0 * 16 * 8), acc0, 0, 0, 0);
      acc1 = __builtin_amdgcn_mfma_f32_16x16x32_bf16(af, *(const bh8*)(vk + 1 * 16 * 8), acc1, 0, 0, 0);
      acc2 = __builtin_amdgcn_mfma_f32_16x16x32_bf16(af, *(const bh8*)(vk + 2 * 16 * 8), acc2, 0, 0, 0);
      acc3 = __builtin_amdgcn_mfma_f32_16x16x32_bf16(af, *(const bh8*)(vk + 3 * 16 * 8), acc3, 0, 0, 0);
    }
  }
  const int orow = a0 + wv * 16 + lgrp * 4;
#pragma unroll
  for (int r = 0; r < 4; ++r) {
    float sc = 1.0f;
    if (PBM) {
      size_t li = (size_t)bh * NT + orow + r;
      sc = 1.0f / (lsumP[li] + lsumP[65536 + li]);
    }
    size_t rb = ((size_t)(b * NT + orow + r)) * DMODEL + hh * 64 + lrow;
    float d0 = acc0[r] * sc, d1 = acc1[r] * sc, d2 = acc2[r] * sc, d3 = acc3[r] * sc;
    deta[rb + 0]  = d0; detab[rb + 0]  = f2bf(d0);
    deta[rb + 16] = d1; detab[rb + 16] = f2bf(d1);
    deta[rb + 32] = d2; detab[rb + 32] = f2bf(d2);
    deta[rb + 48] = d3; detab[rb + 48] = f2bf(d3);
  }
}

// ---------------- final gemm ----------------
__global__ __launch_bounds__(256) void k_gout(
    const unsigned short* __restrict__ A, const unsigned short* __restrict__ B,
    float* __restrict__ C, int K, int N,
    const float* __restrict__ X, const float* __restrict__ bias)
{
  const int bm = blockIdx.y * 128, bn = blockIdx.x * 128;
  const int tid = threadIdx.x, lane = tid & 63, wv = tid >> 6;
  const int wr = wv >> 1, wc = wv & 1;
  const int lrow = lane & 15, lgrp = lane >> 4;
  fx4 acc[4][4];
#pragma unroll
  for (int m = 0; m < 4; ++m)
#pragma unroll
    for (int n = 0; n < 4; ++n) acc[m][n] = (fx4){0.f, 0.f, 0.f, 0.f};
  const unsigned short* Ab = A + (size_t)(bm + wr * 64 + lrow) * K + lgrp * 8;
  const unsigned short* Bb = B + (size_t)(bn + wc * 64 + lrow) * K + lgrp * 8;
  for (int k0 = 0; k0 < K; k0 += 32) {
    bh8 af[4], bf[4];
#pragma unroll
    for (int m = 0; m < 4; ++m) af[m] = *(const bh8*)(Ab + (size_t)m * 16 * K + k0);
#pragma unroll
    for (int n = 0; n < 4; ++n) bf[n] = *(const bh8*)(Bb + (size_t)n * 16 * K + k0);
#pragma unroll
    for (int m = 0; m < 4; ++m)
#pragma unroll
      for (int n = 0; n < 4; ++n)
        acc[m][n] = __builtin_amdgcn_mfma_f32_16x16x32_bf16(af[m], bf[n], acc[m][n], 0, 0, 0);
  }
#pragma unroll
  for (int m = 0; m < 4; ++m)
#pragma unroll
    for (int n = 0; n < 4; ++n)
#pragma unroll
      for (int r = 0; r < 4; ++r) {
        int row = bm + wr * 64 + m * 16 + lgrp * 4 + r;
        int col = bn + wc * 64 + n * 16 + lrow;
        C[(size_t)row * N + col] = acc[m][n][r] + X[(size_t)row * N + col] + bias[col];
      }
}

extern "C" void kernel_launch(void* const* d_in, const int* in_sizes, int n_in,
                              void* d_out, int out_size, void* d_ws, size_t ws_size,
                              hipStream_t stream) {
  const float* x   = (const float*)d_in[0];
  const float* aux = (const float*)d_in[1];
  const float* pos = (const float*)d_in[2];
  const float* Wq  = (const float*)d_in[3];
  const float* bq  = (const float*)d_in[4];
  const float* Wk  = (const float*)d_in[5];
  const float* bk  = (const float*)d_in[6];
  const float* Wv  = (const float*)d_in[7];
  const float* bv  = (const float*)d_in[8];
  const float* Wqa = (const float*)d_in[9];
  const float* bqa = (const float*)d_in[10];
  const float* Wka = (const float*)d_in[11];
  const float* bka = (const float*)d_in[12];
  const float* Wqp = (const float*)d_in[13];
  const float* bqp = (const float*)d_in[14];
  const float* Wkp = (const float*)d_in[15];
  const float* bkp = (const float*)d_in[16];
  const float* WO  = (const float*)d_in[17];
  const float* bO  = (const float*)d_in[18];
  const float* w   = (const float*)d_in[19];
  const float* wa  = (const float*)d_in[20];
  const float* wp  = (const float*)d_in[21];
  const int*   gdep = (const int*)d_in[22];

  float* out  = (float*)d_out;                        // [8,1024,512]
  float* attn = out + (size_t)4194304;                // [8,1024,8,1024]
  float* deta = out + (size_t)71303168;               // [8,1024,512]

  // cm activations live in the (not yet written) attn region
  unsigned short* xcm   = (unsigned short*)attn;              // [64][8192][8]
  unsigned short* auxcm = xcm + 4194304;                      // [32][8192][8]
  unsigned short* poscm = auxcm + 2097152;                    // [16][8192][8]

  // aliases: Qf -> out slot, Kf -> deta slot (both dead before overwrite)
  unsigned short* Qf = (unsigned short*)out;
  unsigned short* Kf = (unsigned short*)deta;

  float* ws = (float*)d_ws;
  float* lsumP = ws;                                        // 2*65536 f32
  unsigned short* Wqkvcm = (unsigned short*)(ws + 131072);  // 786432
  unsigned short* WO_mb  = Wqkvcm + 786432;                 // 262144
  unsigned short* Wacm   = WO_mb + 262144;                  // 131072
  unsigned short* Wpcm   = Wacm + 131072;                   // 32768
  unsigned short* Vrow   = Wpcm + 32768;                    // 4194304
  unsigned short* Vc     = Vrow + 4194304;                  // 4194304
  unsigned short* qcf    = Vc + 4194304;                    // 4194304
  unsigned short* kcf    = qcf + 4194304;                   // 4194304
  unsigned short* detab  = kcf + 4194304;                   // 4194304
  unsigned short* PB     = detab + 4194304;                 // 67108864 (if ws large)

  const size_t NEED_PB = 179109888ull;
  const bool pbm = (ws_size >= NEED_PB);

  k_prep<<<512, 256, 0, stream>>>(Wq, Wk, Wv, WO, gdep, Wqa, Wka, Wqp, Wkp,
                                  Wqkvcm, WO_mb, Wacm, Wpcm, qcf, kcf);
  k_tocm<<<dim3(128, 8), 256, 0, stream>>>(x, xcm, 8192, 512);
  k_tocm<<<dim3(128, 4), 256, 0, stream>>>(aux, auxcm, 8192, 256);
  k_tocm<<<dim3(128, 2), 256, 0, stream>>>(pos, poscm, 8192, 128);
  k_gqkv<<<dim3(12, 64), 256, 0, stream>>>(xcm, Wqkvcm, bq, bk, bv, w, Qf, Kf, Vrow);
  k_gaux<<<dim3(4, 64), 256, 0, stream>>>(auxcm, Wacm, bqa, bka, wa, qcf, kcf);
  k_gpos<<<dim3(2, 64), 256, 0, stream>>>(poscm, Wpcm, bqp, bkp, wp, qcf, kcf);
  k_vtr<<<dim3(16, 64), 256, 0, stream>>>(Vrow, Vc);
  if (pbm) {
    k_sim<true><<<2048, 256, 0, stream>>>(Qf, Kf, qcf, kcf, lsumP, attn, PB);
    k_pv<true><<<dim3(16, 64), 256, 0, stream>>>(Vc, lsumP, attn, PB, deta, detab);
  } else {
    k_sim<false><<<2048, 256, 0, stream>>>(Qf, Kf, qcf, kcf, lsumP, attn, PB);
    k_pv<false><<<dim3(16, 64), 256, 0, stream>>>(Vc, lsumP, attn, PB, deta, detab);
  }
  k_gout<<<dim3(4, 64), 256, 0, stream>>>(detab, WO_mb, out, 512, 512, x, bO);
}

// Round 12
// 403.641 us; speedup vs baseline: 1.3923x; 1.3923x over previous
//
#include <hip/hip_runtime.h>
#include <math.h>

#define NB 8
#define NH 8
#define NT 1024
#define DMODEL 512

typedef short bh8 __attribute__((ext_vector_type(8)));   // 8 bf16 (4 VGPRs)
typedef float fx4 __attribute__((ext_vector_type(4)));   // MFMA accumulator

__device__ __forceinline__ unsigned short f2bf(float f) {
  union { float f; unsigned int u; } v; v.f = f;
  unsigned int u = v.u + 0x7FFFu + ((v.u >> 16) & 1u);
  return (unsigned short)(u >> 16);
}
__device__ __forceinline__ float bf2f(unsigned short h) {
  union { unsigned int u; float f; } v; v.u = ((unsigned int)h) << 16;
  return v.f;
}

// ---------------- prep: weights -> masked bf16 (cm for gemm B), zero pad chunks ----------------
__global__ __launch_bounds__(256) void k_prep(
    const float* __restrict__ Wq, const float* __restrict__ Wk,
    const float* __restrict__ Wv, const float* __restrict__ WO,
    const int* __restrict__ g,
    const float* __restrict__ Wqa, const float* __restrict__ Wka,
    const float* __restrict__ Wqp, const float* __restrict__ Wkp,
    unsigned short* __restrict__ Wqkvcm, unsigned short* __restrict__ WO_mb,
    unsigned short* __restrict__ Wacm, unsigned short* __restrict__ Wpcm,
    unsigned short* __restrict__ qcf, unsigned short* __restrict__ kcf)
{
  int stride = gridDim.x * 256;
  int tid0 = blockIdx.x * 256 + threadIdx.x;
  for (int i = tid0; i < 1536 * 512; i += stride) {
    int m = i & 511;
    int j = i >> 9;
    int k = j & 63;
    int hh = (j >> 6) & 7;
    int qkv = j >> 9;
    const float* W = (qkv == 0) ? Wq : (qkv == 1 ? Wk : Wv);
    float val = W[(hh * 64 + k) * 512 + m] * (float)g[k * 64 + (m & 63)];
    Wqkvcm[((size_t)(m >> 3) * 1536 + j) * 8 + (m & 7)] = f2bf(val);
  }
  for (int i = tid0; i < 512 * 512; i += stride) {
    int d = i & 511, e = i >> 9;
    WO_mb[i] = f2bf(WO[i] * (float)g[(e & 63) * 64 + (d & 63)]);
  }
  for (int i = tid0; i < 512 * 256; i += stride) {
    int a = i & 255, j = i >> 8;
    float val = (j < 256) ? Wqa[j * 256 + a] : Wka[(j - 256) * 256 + a];
    Wacm[((size_t)(a >> 3) * 512 + j) * 8 + (a & 7)] = f2bf(val);
  }
  for (int i = tid0; i < 256 * 128; i += stride) {
    int p = i & 127, j = i >> 7;
    float val = (j < 128) ? Wqp[j * 128 + p] : Wkp[(j - 128) * 128 + p];
    Wpcm[((size_t)(p >> 3) * 256 + j) * 8 + (p & 7)] = f2bf(val);
  }
  for (int i = tid0; i < 64 * 16384; i += stride) {
    int bh = i >> 14, rest = i & 16383;
    size_t addr = (size_t)(bh * 8 + 6) * 8192 + rest;
    qcf[addr] = 0; kcf[addr] = 0;
  }
}

// ---------------- f32 row-major [M][K] -> bf16 chunk-major [K/8][M][8] ----------------
__global__ __launch_bounds__(256) void k_tocm(
    const float* __restrict__ src, unsigned short* __restrict__ dst, int M, int K)
{
  __shared__ unsigned short t16[64][80];
  const int bm = blockIdx.x * 64, bk = blockIdx.y * 64;
  const int tid = threadIdx.x;
  {
    int r = tid >> 2, q = tid & 3;
    const float* sp = src + (size_t)(bm + r) * K + bk + q * 16;
#pragma unroll
    for (int j = 0; j < 4; ++j) {
      float4 v = *(const float4*)(sp + j * 4);
      t16[r][q * 16 + j * 4 + 0] = f2bf(v.x);
      t16[r][q * 16 + j * 4 + 1] = f2bf(v.y);
      t16[r][q * 16 + j * 4 + 2] = f2bf(v.z);
      t16[r][q * 16 + j * 4 + 3] = f2bf(v.w);
    }
  }
  __syncthreads();
  {
    int cq = tid >> 5, rr = tid & 31;
#pragma unroll
    for (int h = 0; h < 2; ++h) {
      int r2 = rr + h * 32;
      unsigned short* dp = dst + ((size_t)((bk >> 3) + cq) * M + bm + r2) * 8;
      *(int4*)dp = *(const int4*)&t16[r2][cq * 8];
    }
  }
}

// ---------------- fused QKV gemm ----------------
__global__ __launch_bounds__(256) void k_gqkv(
    const unsigned short* __restrict__ Acm, const unsigned short* __restrict__ Bcm,
    const float* __restrict__ bq, const float* __restrict__ bk, const float* __restrict__ bv,
    const float* __restrict__ w,
    unsigned short* __restrict__ Qf, unsigned short* __restrict__ Kf,
    unsigned short* __restrict__ Vrow)
{
  const int M = 8192, N = 1536, K = 512;
  const int bm = blockIdx.y * 128, bn = blockIdx.x * 128;
  const int tid = threadIdx.x, lane = tid & 63, wv = tid >> 6;
  const int wr = wv >> 1, wc = wv & 1;
  const int lrow = lane & 15, lgrp = lane >> 4;
  fx4 acc[4][4];
#pragma unroll
  for (int m = 0; m < 4; ++m)
#pragma unroll
    for (int n = 0; n < 4; ++n) acc[m][n] = (fx4){0.f, 0.f, 0.f, 0.f};
  for (int k0 = 0; k0 < K; k0 += 32) {
    bh8 af[4], bf[4];
#pragma unroll
    for (int m = 0; m < 4; ++m)
      af[m] = *(const bh8*)(Acm + (((size_t)((k0 >> 3) + lgrp)) * M + bm + wr * 64 + m * 16 + lrow) * 8);
#pragma unroll
    for (int n = 0; n < 4; ++n)
      bf[n] = *(const bh8*)(Bcm + (((size_t)((k0 >> 3) + lgrp)) * N + bn + wc * 64 + n * 16 + lrow) * 8);
#pragma unroll
    for (int m = 0; m < 4; ++m)
#pragma unroll
      for (int n = 0; n < 4; ++n)
        acc[m][n] = __builtin_amdgcn_mfma_f32_16x16x32_bf16(af[m], bf[n], acc[m][n], 0, 0, 0);
  }
  const int qkv = bn >> 9;
  const int hh = ((bn + wc * 64) >> 6) & 7;
  const float w0 = w[0];
  const float* bias = (qkv == 0) ? bq : (qkv == 1 ? bk : bv);
  float bvals[4];
#pragma unroll
  for (int n = 0; n < 4; ++n) bvals[n] = bias[hh * 64 + n * 16 + lrow];
#pragma unroll
  for (int m = 0; m < 4; ++m)
#pragma unroll
    for (int r = 0; r < 4; ++r) {
      int row = bm + wr * 64 + m * 16 + lgrp * 4 + r;
      int b = row >> 10, t = row & 1023;
      int bh = b * 8 + hh;
      float v0 = acc[m][0][r] + bvals[0];
      float v1 = acc[m][1][r] + bvals[1];
      float v2 = acc[m][2][r] + bvals[2];
      float v3 = acc[m][3][r] + bvals[3];
      if (qkv < 2) {
        float p = v0 * v0 + v1 * v1 + v2 * v2 + v3 * v3;
        p += __shfl_xor(p, 1); p += __shfl_xor(p, 2);
        p += __shfl_xor(p, 4); p += __shfl_xor(p, 8);
        float rn = 1.0f / fmaxf(sqrtf(p), 1e-12f);
        if (qkv == 0) rn *= w0;
        unsigned short* dst = (qkv == 0) ? Qf : Kf;
        size_t base = (size_t)bh * 65536 + (size_t)(lrow >> 3) * 8192 + (size_t)t * 8 + (lrow & 7);
        dst[base + 0 * 16384] = f2bf(v0 * rn);
        dst[base + 1 * 16384] = f2bf(v1 * rn);
        dst[base + 2 * 16384] = f2bf(v2 * rn);
        dst[base + 3 * 16384] = f2bf(v3 * rn);
      } else {
        size_t vb = ((size_t)bh * NT + t) * 64 + lrow;
        Vrow[vb + 0]  = f2bf(v0);
        Vrow[vb + 16] = f2bf(v1);
        Vrow[vb + 32] = f2bf(v2);
        Vrow[vb + 48] = f2bf(v3);
      }
    }
}

// ---------------- fused aux gemm ----------------
__global__ __launch_bounds__(256) void k_gaux(
    const unsigned short* __restrict__ Acm, const unsigned short* __restrict__ Bcm,
    const float* __restrict__ bqa, const float* __restrict__ bka,
    const float* __restrict__ wa,
    unsigned short* __restrict__ qcf, unsigned short* __restrict__ kcf)
{
  const int M = 8192, N = 512, K = 256;
  const int bm = blockIdx.y * 128, bn = blockIdx.x * 128;
  const int tid = threadIdx.x, lane = tid & 63, wv = tid >> 6;
  const int wr = wv >> 1, wc = wv & 1;
  const int lrow = lane & 15, lgrp = lane >> 4;
  fx4 acc[4][4];
#pragma unroll
  for (int m = 0; m < 4; ++m)
#pragma unroll
    for (int n = 0; n < 4; ++n) acc[m][n] = (fx4){0.f, 0.f, 0.f, 0.f};
  for (int k0 = 0; k0 < K; k0 += 32) {
    bh8 af[4], bf[4];
#pragma unroll
    for (int m = 0; m < 4; ++m)
      af[m] = *(const bh8*)(Acm + (((size_t)((k0 >> 3) + lgrp)) * M + bm + wr * 64 + m * 16 + lrow) * 8);
#pragma unroll
    for (int n = 0; n < 4; ++n)
      bf[n] = *(const bh8*)(Bcm + (((size_t)((k0 >> 3) + lgrp)) * N + bn + wc * 64 + n * 16 + lrow) * 8);
#pragma unroll
    for (int m = 0; m < 4; ++m)
#pragma unroll
      for (int n = 0; n < 4; ++n)
        acc[m][n] = __builtin_amdgcn_mfma_f32_16x16x32_bf16(af[m], bf[n], acc[m][n], 0, 0, 0);
  }
  const int isK = (bn >> 8) & 1;
  const int hh0 = (((bn & 255) + wc * 64) >> 5) & 7;
  const float wa0 = wa[0];
  const float* bias = isK ? bka : bqa;
  float bvals[4];
#pragma unroll
  for (int n = 0; n < 4; ++n) bvals[n] = bias[(hh0 + (n >> 1)) * 32 + (n & 1) * 16 + lrow];
  unsigned short* dst = isK ? kcf : qcf;
  const float scale = isK ? 1.0f : wa0;
#pragma unroll
  for (int m = 0; m < 4; ++m)
#pragma unroll
    for (int r = 0; r < 4; ++r) {
      int row = bm + wr * 64 + m * 16 + lgrp * 4 + r;
      int b = row >> 10, t = row & 1023;
      float v0 = acc[m][0][r] + bvals[0];
      float v1 = acc[m][1][r] + bvals[1];
      float v2 = acc[m][2][r] + bvals[2];
      float v3 = acc[m][3][r] + bvals[3];
      float plo = v0 * v0 + v1 * v1;
      float phi = v2 * v2 + v3 * v3;
      plo += __shfl_xor(plo, 1); plo += __shfl_xor(plo, 2);
      plo += __shfl_xor(plo, 4); plo += __shfl_xor(plo, 8);
      phi += __shfl_xor(phi, 1); phi += __shfl_xor(phi, 2);
      phi += __shfl_xor(phi, 4); phi += __shfl_xor(phi, 8);
      float rlo = scale / fmaxf(sqrtf(plo), 1e-12f);
      float rhi = scale / fmaxf(sqrtf(phi), 1e-12f);
      size_t b0 = (size_t)(b * 8 + hh0) * 65536 + (size_t)(lrow >> 3) * 8192 + (size_t)t * 8 + (lrow & 7);
      size_t b1 = (size_t)(b * 8 + hh0 + 1) * 65536 + (size_t)(lrow >> 3) * 8192 + (size_t)t * 8 + (lrow & 7);
      dst[b0 + 0]     = f2bf(v0 * rlo);
      dst[b0 + 16384] = f2bf(v1 * rlo);
      dst[b1 + 0]     = f2bf(v2 * rhi);
      dst[b1 + 16384] = f2bf(v3 * rhi);
    }
}

// ---------------- fused pos gemm ----------------
__global__ __launch_bounds__(256) void k_gpos(
    const unsigned short* __restrict__ Acm, const unsigned short* __restrict__ Bcm,
    const float* __restrict__ bqp, const float* __restrict__ bkp,
    const float* __restrict__ wp,
    unsigned short* __restrict__ qcf, unsigned short* __restrict__ kcf)
{
  const int M = 8192, N = 256, K = 128;
  const int bm = blockIdx.y * 128, bn = blockIdx.x * 128;
  const int tid = threadIdx.x, lane = tid & 63, wv = tid >> 6;
  const int wr = wv >> 1, wc = wv & 1;
  const int lrow = lane & 15, lgrp = lane >> 4;
  fx4 acc[4][4];
#pragma unroll
  for (int m = 0; m < 4; ++m)
#pragma unroll
    for (int n = 0; n < 4; ++n) acc[m][n] = (fx4){0.f, 0.f, 0.f, 0.f};
  for (int k0 = 0; k0 < K; k0 += 32) {
    bh8 af[4], bf[4];
#pragma unroll
    for (int m = 0; m < 4; ++m)
      af[m] = *(const bh8*)(Acm + (((size_t)((k0 >> 3) + lgrp)) * M + bm + wr * 64 + m * 16 + lrow) * 8);
#pragma unroll
    for (int n = 0; n < 4; ++n)
      bf[n] = *(const bh8*)(Bcm + (((size_t)((k0 >> 3) + lgrp)) * N + bn + wc * 64 + n * 16 + lrow) * 8);
#pragma unroll
    for (int m = 0; m < 4; ++m)
#pragma unroll
      for (int n = 0; n < 4; ++n)
        acc[m][n] = __builtin_amdgcn_mfma_f32_16x16x32_bf16(af[m], bf[n], acc[m][n], 0, 0, 0);
  }
  const int isK = (bn >> 7) & 1;
  const int bh0 = (((bn & 127) + wc * 64) >> 4) & 7;
  const float wp0 = wp[0];
  const float* bias = isK ? bkp : bqp;
  float bvals[4];
#pragma unroll
  for (int n = 0; n < 4; ++n) bvals[n] = bias[(bh0 + n) * 16 + lrow];
  unsigned short* dst = isK ? kcf : qcf;
  const float scale = isK ? 1.0f : wp0;
#pragma unroll
  for (int m = 0; m < 4; ++m)
#pragma unroll
    for (int r = 0; r < 4; ++r) {
      int row = bm + wr * 64 + m * 16 + lgrp * 4 + r;
      int b = row >> 10, t = row & 1023;
      float v[4];
      v[0] = acc[m][0][r] + bvals[0];
      v[1] = acc[m][1][r] + bvals[1];
      v[2] = acc[m][2][r] + bvals[2];
      v[3] = acc[m][3][r] + bvals[3];
#pragma unroll
      for (int n = 0; n < 4; ++n) {
        float p = v[n] * v[n];
        p += __shfl_xor(p, 1); p += __shfl_xor(p, 2);
        p += __shfl_xor(p, 4); p += __shfl_xor(p, 8);
        float rn = scale / fmaxf(sqrtf(p), 1e-12f);
        size_t addr = (size_t)(b * 8 + bh0 + n) * 65536 + (size_t)(4 + (lrow >> 3)) * 8192
                    + (size_t)t * 8 + (lrow & 7);
        dst[addr] = f2bf(v[n] * rn);
      }
    }
}

// ---------------- V transpose ----------------
__global__ __launch_bounds__(256) void k_vtr(
    const unsigned short* __restrict__ Vrow, unsigned short* __restrict__ Vc)
{
  __shared__ unsigned short tile[64][72];
  const int tt = blockIdx.x, bh = blockIdx.y;
  const int tid = threadIdx.x;
  const int r = tid & 63, g = tid >> 6;
  const unsigned short* src = Vrow + ((size_t)bh * NT + tt * 64 + r) * 64 + g * 16;
  int4 v0 = *(const int4*)(src);
  int4 v1 = *(const int4*)(src + 8);
  const unsigned short* pv0 = (const unsigned short*)&v0;
  const unsigned short* pv1 = (const unsigned short*)&v1;
#pragma unroll
  for (int j = 0; j < 8; ++j) tile[g * 16 + j][r] = pv0[j];
#pragma unroll
  for (int j = 0; j < 8; ++j) tile[g * 16 + 8 + j][r] = pv1[j];
  __syncthreads();
  unsigned short* dst0 = Vc + ((size_t)(bh * 128 + tt * 8 + g * 2) * 64 + r) * 8;
  unsigned short* dst1 = Vc + ((size_t)(bh * 128 + tt * 8 + g * 2 + 1) * 64 + r) * 8;
  *(int4*)dst0 = *(const int4*)&tile[r][g * 16];
  *(int4*)(dst1) = *(const int4*)&tile[r][g * 16 + 8];
}

// ---------------- slide body (EDGE: full cnt; else cnt==17) ----------------
template<bool EDGE, bool PBM>
__device__ __forceinline__ void slide_body(
    const float (*Se)[81], const unsigned short (*Pd)[66],
    int a0, int c0, int b, int hh, int wv, int lane, int base_cl,
    float* lacc, float* __restrict__ attn, unsigned short* __restrict__ PB)
{
  float dval = 0.f;
  {
    int rr = wv * 16 + (lane & 15);
#pragma unroll
    for (int u = 0; u <= 16; ++u) dval += Se[rr + u][u];
  }
  float num = 0.f;
#pragma unroll
  for (int s = 0; s < 16; ++s) {
    int a_l = wv * 16 + s;
    int c_l = (base_cl + s) & 63;
    if (s == 0) {
      num = 0.f;
#pragma unroll
      for (int u = 0; u <= 16; ++u) num += Se[a_l + u][c_l + u];
    } else {
      int cm1 = (c_l == 0) ? 0 : (c_l - 1);
      float up = Se[a_l + 16][c_l + 16] - Se[a_l - 1][cm1];
      float dS = __shfl(dval, s);
      num = (c_l == 0) ? dS : (num + up);
    }
    int a = a0 + a_l, c = c0 + c_l;
    float sim;
    if (EDGE) {
      int mn = min(a, c), mx = max(a, c);
      float cntf = (float)(min(8, mn) + min(8, 1023 - mx) + 1);
      sim = num * __builtin_amdgcn_rcpf(cntf) + bf2f(Pd[a_l][c_l]);
    } else {
      sim = num * (1.0f / 17.0f) + bf2f(Pd[a_l][c_l]);
    }
    float pe = __expf(sim);
    lacc[s] += pe;
    size_t oidx = (((size_t)(b * NT + a)) * NH + hh) * NT + c;
    if (PBM) PB[oidx] = f2bf(pe);
    else     attn[oidx] = pe;
  }
}

// ---------------- sim kernel: ctg=2, XCD-swizzled, chunk-major frags ----------------
// grid 2048 flat. wgid = (flat&7)*256 + flat>>3. bh=wgid>>5, ctg=(wgid>>4)&1, at=wgid&15
// NOTE: no __launch_bounds__ min-waves — forcing 4 waves/SIMD (r11) cut VGPR 120->64 and
// raised resident blocks -> L2 thrash (FETCH 16.5->411 MB), k_sim 179->330 us. Occupancy
// and L2 locality trade directly here; this config is the measured optimum.
template<bool PBM>
__global__ __launch_bounds__(256) void k_sim(
    const unsigned short* __restrict__ Qf, const unsigned short* __restrict__ Kf,
    const unsigned short* __restrict__ qcf, const unsigned short* __restrict__ kcf,
    float* __restrict__ lsumP, float* __restrict__ attn, unsigned short* __restrict__ PB)
{
  __shared__ float Se[80][81];
  __shared__ unsigned short Pd[64][66];
  const int flat = blockIdx.x;
  const int wgid = (flat & 7) * 256 + (flat >> 3);
  const int bh = wgid >> 5;
  const int ctg = (wgid >> 4) & 1;
  const int at = wgid & 15;
  const int a0 = at * 64;
  const int b = bh >> 3, hh = bh & 7;
  const int tid = threadIdx.x;
  const int lane = tid & 63, wv = tid >> 6;
  const int lrow16 = lane & 15, lgrp = lane >> 4;
  const bh8 zfrag = {0, 0, 0, 0, 0, 0, 0, 0};
  const int base_cl = (wv * 16 + lane) & 63;
  float lacc[16];
#pragma unroll
  for (int s = 0; s < 16; ++s) lacc[s] = 0.f;

  const unsigned short* Qc = Qf + (size_t)(bh * 8 + lgrp) * NT * 8;
  const unsigned short* Kc = Kf + (size_t)(bh * 8 + lgrp) * NT * 8;

  bh8 qa0, qa1;
  {
    const unsigned short* qb = qcf + ((size_t)(bh * 8 + lgrp) * NT + a0 + wv * 16 + lrow16) * 8;
    qa0 = *(const bh8*)(qb);
    qa1 = *(const bh8*)(qb + (size_t)4 * NT * 8);
  }

  for (int ct = ctg * 8; ct < ctg * 8 + 8; ++ct) {
    const int c0 = ct * 64;
    __syncthreads();

#pragma unroll
    for (int i = 0; i < 7; ++i) {
      int tt = wv + 4 * i;
      if (tt < 25) {
        int tr = tt / 5, tc = tt % 5;
        int ar = a0 - 8 + tr * 16 + lrow16;
        int kr = c0 - 8 + tc * 16 + lrow16;
        bool av = (unsigned)ar < (unsigned)NT;
        bool bv = (unsigned)kr < (unsigned)NT;
        const unsigned short* ap = Qc + (size_t)(av ? ar : 0) * 8;
        const unsigned short* bp = Kc + (size_t)(bv ? kr : 0) * 8;
        bh8 af0 = av ? *(const bh8*)(ap) : zfrag;
        bh8 af1 = av ? *(const bh8*)(ap + (size_t)4 * NT * 8) : zfrag;
        bh8 bf0 = bv ? *(const bh8*)(bp) : zfrag;
        bh8 bf1 = bv ? *(const bh8*)(bp + (size_t)4 * NT * 8) : zfrag;
        fx4 acc = {0.f, 0.f, 0.f, 0.f};
        acc = __builtin_amdgcn_mfma_f32_16x16x32_bf16(af0, bf0, acc, 0, 0, 0);
        acc = __builtin_amdgcn_mfma_f32_16x16x32_bf16(af1, bf1, acc, 0, 0, 0);
#pragma unroll
        for (int r = 0; r < 4; ++r)
          Se[tr * 16 + lgrp * 4 + r][tc * 16 + lrow16] = acc[r];
      }
    }

#pragma unroll
    for (int n = 0; n < 4; ++n) {
      const unsigned short* kb = kcf + ((size_t)(bh * 8 + lgrp) * NT + c0 + n * 16 + lrow16) * 8;
      bh8 kb0 = *(const bh8*)(kb);
      bh8 kb1 = *(const bh8*)(kb + (size_t)4 * NT * 8);
      fx4 pacc = {0.f, 0.f, 0.f, 0.f};
      pacc = __builtin_amdgcn_mfma_f32_16x16x32_bf16(qa0, kb0, pacc, 0, 0, 0);
      pacc = __builtin_amdgcn_mfma_f32_16x16x32_bf16(qa1, kb1, pacc, 0, 0, 0);
#pragma unroll
      for (int r = 0; r < 4; ++r)
        Pd[wv * 16 + lgrp * 4 + r][n * 16 + lrow16] = f2bf(pacc[r]);
    }

    __syncthreads();

    bool edge = (ct == 0) || (ct == 15) || (at == 0) || (at == 15);
    if (edge)
      slide_body<true, PBM>(Se, Pd, a0, c0, b, hh, wv, lane, base_cl, lacc, attn, PB);
    else
      slide_body<false, PBM>(Se, Pd, a0, c0, b, hh, wv, lane, base_cl, lacc, attn, PB);
  }

#pragma unroll
  for (int s = 0; s < 16; ++s) {
    float v = lacc[s];
#pragma unroll
    for (int off = 32; off; off >>= 1) v += __shfl_xor(v, off);
    if (lane == 0)
      lsumP[(size_t)ctg * 65536 + (size_t)bh * NT + a0 + wv * 16 + s] = v;
  }
}

// ---------------- normalize attn + PV via MFMA ----------------
template<bool PBM>
__global__ __launch_bounds__(256) void k_pv(
    const unsigned short* __restrict__ Vc, const float* __restrict__ lsumP,
    float* __restrict__ attn, const unsigned short* __restrict__ PB,
    float* __restrict__ deta, unsigned short* __restrict__ detab)
{
  const int at = blockIdx.x, bh = blockIdx.y;
  const int a0 = at * 64;
  const int b = bh >> 3, hh = bh & 7;
  const int tid = threadIdx.x, lane = tid & 63, wv = tid >> 6;
  const int lrow = lane & 15, lgrp = lane >> 4;
  const int arow = a0 + wv * 16 + lrow;
  const size_t lidx = (size_t)bh * NT + arow;
  const float rl = 1.0f / (lsumP[lidx] + lsumP[65536 + lidx]);
  fx4 acc0 = {0.f,0.f,0.f,0.f}, acc1 = {0.f,0.f,0.f,0.f};
  fx4 acc2 = {0.f,0.f,0.f,0.f}, acc3 = {0.f,0.f,0.f,0.f};
  float* arowp = attn + (((size_t)(b * NT + arow)) * NH + hh) * NT;
  const unsigned short* pbrow = PBM ? (PB + (((size_t)(b * NT + arow)) * NH + hh) * NT) : nullptr;
  for (int ct = 0; ct < 16; ++ct) {
    const int c0 = ct * 64;
#pragma unroll
    for (int kh = 0; kh < 2; ++kh) {
      bh8 af;
      if (PBM) {
        af = *(const bh8*)(pbrow + c0 + kh * 32 + lgrp * 8);
        const unsigned short* ap = (const unsigned short*)&af;
        float4 o0, o1;
        o0.x = bf2f(ap[0]) * rl; o0.y = bf2f(ap[1]) * rl;
        o0.z = bf2f(ap[2]) * rl; o0.w = bf2f(ap[3]) * rl;
        o1.x = bf2f(ap[4]) * rl; o1.y = bf2f(ap[5]) * rl;
        o1.z = bf2f(ap[6]) * rl; o1.w = bf2f(ap[7]) * rl;
        *(float4*)(arowp + c0 + kh * 32 + lgrp * 8) = o0;
        *(float4*)(arowp + c0 + kh * 32 + lgrp * 8 + 4) = o1;
      } else {
        float* pp = arowp + c0 + kh * 32 + lgrp * 8;
        float4 p0 = *(float4*)pp;
        float4 p1 = *(float4*)(pp + 4);
        p0.x *= rl; p0.y *= rl; p0.z *= rl; p0.w *= rl;
        p1.x *= rl; p1.y *= rl; p1.z *= rl; p1.w *= rl;
        *(float4*)pp = p0;
        *(float4*)(pp + 4) = p1;
        unsigned short* afp = (unsigned short*)&af;
        afp[0] = f2bf(p0.x); afp[1] = f2bf(p0.y); afp[2] = f2bf(p0.z); afp[3] = f2bf(p0.w);
        afp[4] = f2bf(p1.x); afp[5] = f2bf(p1.y); afp[6] = f2bf(p1.z); afp[7] = f2bf(p1.w);
      }
      const unsigned short* vk = Vc + ((size_t)(bh * 128 + (c0 >> 3) + kh * 4 + lgrp) * 64 + lrow) * 8;
      acc0 = __builtin_amdgcn_mfma_f32_16x16x32_bf16(af, *(const bh8*)(vk + 0 * 16 * 8), acc0, 0, 0, 0);
      acc1 = __builtin_amdgcn_mfma_f32_16x16x32_bf16(af, *(const bh8*)(vk + 1 * 16 * 8), acc1, 0, 0, 0);
      acc2 = __builtin_amdgcn_mfma_f32_16x16x32_bf16(af, *(const bh8*)(vk + 2 * 16 * 8), acc2, 0, 0, 0);
      acc3 = __builtin_amdgcn_mfma_f32_16x16x32_bf16(af, *(const bh8*)(vk + 3 * 16 * 8), acc3, 0, 0, 0);
    }
  }
  const int orow = a0 + wv * 16 + lgrp * 4;
#pragma unroll
  for (int r = 0; r < 4; ++r) {
    float sc = 1.0f;
    if (PBM) {
      size_t li = (size_t)bh * NT + orow + r;
      sc = 1.0f / (lsumP[li] + lsumP[65536 + li]);
    }
    size_t rb = ((size_t)(b * NT + orow + r)) * DMODEL + hh * 64 + lrow;
    float d0 = acc0[r] * sc, d1 = acc1[r] * sc, d2 = acc2[r] * sc, d3 = acc3[r] * sc;
    deta[rb + 0]  = d0; detab[rb + 0]  = f2bf(d0);
    deta[rb + 16] = d1; detab[rb + 16] = f2bf(d1);
    deta[rb + 32] = d2; detab[rb + 32] = f2bf(d2);
    deta[rb + 48] = d3; detab[rb + 48] = f2bf(d3);
  }
}

// ---------------- final gemm ----------------
__global__ __launch_bounds__(256) void k_gout(
    const unsigned short* __restrict__ A, const unsigned short* __restrict__ B,
    float* __restrict__ C, int K, int N,
    const float* __restrict__ X, const float* __restrict__ bias)
{
  const int bm = blockIdx.y * 128, bn = blockIdx.x * 128;
  const int tid = threadIdx.x, lane = tid & 63, wv = tid >> 6;
  const int wr = wv >> 1, wc = wv & 1;
  const int lrow = lane & 15, lgrp = lane >> 4;
  fx4 acc[4][4];
#pragma unroll
  for (int m = 0; m < 4; ++m)
#pragma unroll
    for (int n = 0; n < 4; ++n) acc[m][n] = (fx4){0.f, 0.f, 0.f, 0.f};
  const unsigned short* Ab = A + (size_t)(bm + wr * 64 + lrow) * K + lgrp * 8;
  const unsigned short* Bb = B + (size_t)(bn + wc * 64 + lrow) * K + lgrp * 8;
  for (int k0 = 0; k0 < K; k0 += 32) {
    bh8 af[4], bf[4];
#pragma unroll
    for (int m = 0; m < 4; ++m) af[m] = *(const bh8*)(Ab + (size_t)m * 16 * K + k0);
#pragma unroll
    for (int n = 0; n < 4; ++n) bf[n] = *(const bh8*)(Bb + (size_t)n * 16 * K + k0);
#pragma unroll
    for (int m = 0; m < 4; ++m)
#pragma unroll
      for (int n = 0; n < 4; ++n)
        acc[m][n] = __builtin_amdgcn_mfma_f32_16x16x32_bf16(af[m], bf[n], acc[m][n], 0, 0, 0);
  }
#pragma unroll
  for (int m = 0; m < 4; ++m)
#pragma unroll
    for (int n = 0; n < 4; ++n)
#pragma unroll
      for (int r = 0; r < 4; ++r) {
        int row = bm + wr * 64 + m * 16 + lgrp * 4 + r;
        int col = bn + wc * 64 + n * 16 + lrow;
        C[(size_t)row * N + col] = acc[m][n][r] + X[(size_t)row * N + col] + bias[col];
      }
}

extern "C" void kernel_launch(void* const* d_in, const int* in_sizes, int n_in,
                              void* d_out, int out_size, void* d_ws, size_t ws_size,
                              hipStream_t stream) {
  const float* x   = (const float*)d_in[0];
  const float* aux = (const float*)d_in[1];
  const float* pos = (const float*)d_in[2];
  const float* Wq  = (const float*)d_in[3];
  const float* bq  = (const float*)d_in[4];
  const float* Wk  = (const float*)d_in[5];
  const float* bk  = (const float*)d_in[6];
  const float* Wv  = (const float*)d_in[7];
  const float* bv  = (const float*)d_in[8];
  const float* Wqa = (const float*)d_in[9];
  const float* bqa = (const float*)d_in[10];
  const float* Wka = (const float*)d_in[11];
  const float* bka = (const float*)d_in[12];
  const float* Wqp = (const float*)d_in[13];
  const float* bqp = (const float*)d_in[14];
  const float* Wkp = (const float*)d_in[15];
  const float* bkp = (const float*)d_in[16];
  const float* WO  = (const float*)d_in[17];
  const float* bO  = (const float*)d_in[18];
  const float* w   = (const float*)d_in[19];
  const float* wa  = (const float*)d_in[20];
  const float* wp  = (const float*)d_in[21];
  const int*   gdep = (const int*)d_in[22];

  float* out  = (float*)d_out;                        // [8,1024,512]
  float* attn = out + (size_t)4194304;                // [8,1024,8,1024]
  float* deta = out + (size_t)71303168;               // [8,1024,512]

  // cm activations live in the (not yet written) attn region
  unsigned short* xcm   = (unsigned short*)attn;              // [64][8192][8]
  unsigned short* auxcm = xcm + 4194304;                      // [32][8192][8]
  unsigned short* poscm = auxcm + 2097152;                    // [16][8192][8]

  // aliases: Qf -> out slot, Kf -> deta slot (both dead before overwrite)
  unsigned short* Qf = (unsigned short*)out;
  unsigned short* Kf = (unsigned short*)deta;

  float* ws = (float*)d_ws;
  float* lsumP = ws;                                        // 2*65536 f32
  unsigned short* Wqkvcm = (unsigned short*)(ws + 131072);  // 786432
  unsigned short* WO_mb  = Wqkvcm + 786432;                 // 262144
  unsigned short* Wacm   = WO_mb + 262144;                  // 131072
  unsigned short* Wpcm   = Wacm + 131072;                   // 32768
  unsigned short* Vrow   = Wpcm + 32768;                    // 4194304
  unsigned short* Vc     = Vrow + 4194304;                  // 4194304
  unsigned short* qcf    = Vc + 4194304;                    // 4194304
  unsigned short* kcf    = qcf + 4194304;                   // 4194304
  unsigned short* detab  = kcf + 4194304;                   // 4194304
  unsigned short* PB     = detab + 4194304;                 // 67108864 (if ws large)

  const size_t NEED_PB = 179109888ull;
  const bool pbm = (ws_size >= NEED_PB);

  k_prep<<<512, 256, 0, stream>>>(Wq, Wk, Wv, WO, gdep, Wqa, Wka, Wqp, Wkp,
                                  Wqkvcm, WO_mb, Wacm, Wpcm, qcf, kcf);
  k_tocm<<<dim3(128, 8), 256, 0, stream>>>(x, xcm, 8192, 512);
  k_tocm<<<dim3(128, 4), 256, 0, stream>>>(aux, auxcm, 8192, 256);
  k_tocm<<<dim3(128, 2), 256, 0, stream>>>(pos, poscm, 8192, 128);
  k_gqkv<<<dim3(12, 64), 256, 0, stream>>>(xcm, Wqkvcm, bq, bk, bv, w, Qf, Kf, Vrow);
  k_gaux<<<dim3(4, 64), 256, 0, stream>>>(auxcm, Wacm, bqa, bka, wa, qcf, kcf);
  k_gpos<<<dim3(2, 64), 256, 0, stream>>>(poscm, Wpcm, bqp, bkp, wp, qcf, kcf);
  k_vtr<<<dim3(16, 64), 256, 0, stream>>>(Vrow, Vc);
  if (pbm) {
    k_sim<true><<<2048, 256, 0, stream>>>(Qf, Kf, qcf, kcf, lsumP, attn, PB);
    k_pv<true><<<dim3(16, 64), 256, 0, stream>>>(Vc, lsumP, attn, PB, deta, detab);
  } else {
    k_sim<false><<<2048, 256, 0, stream>>>(Qf, Kf, qcf, kcf, lsumP, attn, PB);
    k_pv<false><<<dim3(16, 64), 256, 0, stream>>>(Vc, lsumP, attn, PB, deta, detab);
  }
  k_gout<<<dim3(4, 64), 256, 0, stream>>>(detab, WO_mb, out, 512, 512, x, bO);
}

// Round 13
// 403.040 us; speedup vs baseline: 1.3944x; 1.0015x over previous
//
#include <hip/hip_runtime.h>
#include <math.h>

#define NB 8
#define NH 8
#define NT 1024
#define DMODEL 512

typedef short bh8 __attribute__((ext_vector_type(8)));   // 8 bf16 (4 VGPRs)
typedef float fx4 __attribute__((ext_vector_type(4)));   // MFMA accumulator

__device__ __forceinline__ unsigned short f2bf(float f) {
  union { float f; unsigned int u; } v; v.f = f;
  unsigned int u = v.u + 0x7FFFu + ((v.u >> 16) & 1u);
  return (unsigned short)(u >> 16);
}
__device__ __forceinline__ float bf2f(unsigned short h) {
  union { unsigned int u; float f; } v; v.u = ((unsigned int)h) << 16;
  return v.f;
}

// ---------------- prep: weights -> masked bf16 (cm for gemm B), zero pad chunks ----------------
__global__ __launch_bounds__(256) void k_prep(
    const float* __restrict__ Wq, const float* __restrict__ Wk,
    const float* __restrict__ Wv, const float* __restrict__ WO,
    const int* __restrict__ g,
    const float* __restrict__ Wqa, const float* __restrict__ Wka,
    const float* __restrict__ Wqp, const float* __restrict__ Wkp,
    unsigned short* __restrict__ Wqkvcm, unsigned short* __restrict__ WO_mb,
    unsigned short* __restrict__ Wacm, unsigned short* __restrict__ Wpcm,
    unsigned short* __restrict__ qcf, unsigned short* __restrict__ kcf)
{
  int stride = gridDim.x * 256;
  int tid0 = blockIdx.x * 256 + threadIdx.x;
  for (int i = tid0; i < 1536 * 512; i += stride) {
    int m = i & 511;
    int j = i >> 9;
    int k = j & 63;
    int hh = (j >> 6) & 7;
    int qkv = j >> 9;
    const float* W = (qkv == 0) ? Wq : (qkv == 1 ? Wk : Wv);
    float val = W[(hh * 64 + k) * 512 + m] * (float)g[k * 64 + (m & 63)];
    Wqkvcm[((size_t)(m >> 3) * 1536 + j) * 8 + (m & 7)] = f2bf(val);
  }
  for (int i = tid0; i < 512 * 512; i += stride) {
    int d = i & 511, e = i >> 9;
    WO_mb[i] = f2bf(WO[i] * (float)g[(e & 63) * 64 + (d & 63)]);
  }
  for (int i = tid0; i < 512 * 256; i += stride) {
    int a = i & 255, j = i >> 8;
    float val = (j < 256) ? Wqa[j * 256 + a] : Wka[(j - 256) * 256 + a];
    Wacm[((size_t)(a >> 3) * 512 + j) * 8 + (a & 7)] = f2bf(val);
  }
  for (int i = tid0; i < 256 * 128; i += stride) {
    int p = i & 127, j = i >> 7;
    float val = (j < 128) ? Wqp[j * 128 + p] : Wkp[(j - 128) * 128 + p];
    Wpcm[((size_t)(p >> 3) * 256 + j) * 8 + (p & 7)] = f2bf(val);
  }
  for (int i = tid0; i < 64 * 16384; i += stride) {
    int bh = i >> 14, rest = i & 16383;
    size_t addr = (size_t)(bh * 8 + 6) * 8192 + rest;
    qcf[addr] = 0; kcf[addr] = 0;
  }
}

// ---------------- f32 row-major [M][K] -> bf16 chunk-major [K/8][M][8] ----------------
__global__ __launch_bounds__(256) void k_tocm(
    const float* __restrict__ src, unsigned short* __restrict__ dst, int M, int K)
{
  __shared__ unsigned short t16[64][80];
  const int bm = blockIdx.x * 64, bk = blockIdx.y * 64;
  const int tid = threadIdx.x;
  {
    int r = tid >> 2, q = tid & 3;
    const float* sp = src + (size_t)(bm + r) * K + bk + q * 16;
#pragma unroll
    for (int j = 0; j < 4; ++j) {
      float4 v = *(const float4*)(sp + j * 4);
      t16[r][q * 16 + j * 4 + 0] = f2bf(v.x);
      t16[r][q * 16 + j * 4 + 1] = f2bf(v.y);
      t16[r][q * 16 + j * 4 + 2] = f2bf(v.z);
      t16[r][q * 16 + j * 4 + 3] = f2bf(v.w);
    }
  }
  __syncthreads();
  {
    int cq = tid >> 5, rr = tid & 31;
#pragma unroll
    for (int h = 0; h < 2; ++h) {
      int r2 = rr + h * 32;
      unsigned short* dp = dst + ((size_t)((bk >> 3) + cq) * M + bm + r2) * 8;
      *(int4*)dp = *(const int4*)&t16[r2][cq * 8];
    }
  }
}

// ---------------- fused QKV gemm ----------------
__global__ __launch_bounds__(256) void k_gqkv(
    const unsigned short* __restrict__ Acm, const unsigned short* __restrict__ Bcm,
    const float* __restrict__ bq, const float* __restrict__ bk, const float* __restrict__ bv,
    const float* __restrict__ w,
    unsigned short* __restrict__ Qf, unsigned short* __restrict__ Kf,
    unsigned short* __restrict__ Vrow)
{
  const int M = 8192, N = 1536, K = 512;
  const int bm = blockIdx.y * 128, bn = blockIdx.x * 128;
  const int tid = threadIdx.x, lane = tid & 63, wv = tid >> 6;
  const int wr = wv >> 1, wc = wv & 1;
  const int lrow = lane & 15, lgrp = lane >> 4;
  fx4 acc[4][4];
#pragma unroll
  for (int m = 0; m < 4; ++m)
#pragma unroll
    for (int n = 0; n < 4; ++n) acc[m][n] = (fx4){0.f, 0.f, 0.f, 0.f};
  for (int k0 = 0; k0 < K; k0 += 32) {
    bh8 af[4], bf[4];
#pragma unroll
    for (int m = 0; m < 4; ++m)
      af[m] = *(const bh8*)(Acm + (((size_t)((k0 >> 3) + lgrp)) * M + bm + wr * 64 + m * 16 + lrow) * 8);
#pragma unroll
    for (int n = 0; n < 4; ++n)
      bf[n] = *(const bh8*)(Bcm + (((size_t)((k0 >> 3) + lgrp)) * N + bn + wc * 64 + n * 16 + lrow) * 8);
#pragma unroll
    for (int m = 0; m < 4; ++m)
#pragma unroll
      for (int n = 0; n < 4; ++n)
        acc[m][n] = __builtin_amdgcn_mfma_f32_16x16x32_bf16(af[m], bf[n], acc[m][n], 0, 0, 0);
  }
  const int qkv = bn >> 9;
  const int hh = ((bn + wc * 64) >> 6) & 7;
  const float w0 = w[0];
  const float* bias = (qkv == 0) ? bq : (qkv == 1 ? bk : bv);
  float bvals[4];
#pragma unroll
  for (int n = 0; n < 4; ++n) bvals[n] = bias[hh * 64 + n * 16 + lrow];
#pragma unroll
  for (int m = 0; m < 4; ++m)
#pragma unroll
    for (int r = 0; r < 4; ++r) {
      int row = bm + wr * 64 + m * 16 + lgrp * 4 + r;
      int b = row >> 10, t = row & 1023;
      int bh = b * 8 + hh;
      float v0 = acc[m][0][r] + bvals[0];
      float v1 = acc[m][1][r] + bvals[1];
      float v2 = acc[m][2][r] + bvals[2];
      float v3 = acc[m][3][r] + bvals[3];
      if (qkv < 2) {
        float p = v0 * v0 + v1 * v1 + v2 * v2 + v3 * v3;
        p += __shfl_xor(p, 1); p += __shfl_xor(p, 2);
        p += __shfl_xor(p, 4); p += __shfl_xor(p, 8);
        float rn = 1.0f / fmaxf(sqrtf(p), 1e-12f);
        if (qkv == 0) rn *= w0;
        unsigned short* dst = (qkv == 0) ? Qf : Kf;
        size_t base = (size_t)bh * 65536 + (size_t)(lrow >> 3) * 8192 + (size_t)t * 8 + (lrow & 7);
        dst[base + 0 * 16384] = f2bf(v0 * rn);
        dst[base + 1 * 16384] = f2bf(v1 * rn);
        dst[base + 2 * 16384] = f2bf(v2 * rn);
        dst[base + 3 * 16384] = f2bf(v3 * rn);
      } else {
        size_t vb = ((size_t)bh * NT + t) * 64 + lrow;
        Vrow[vb + 0]  = f2bf(v0);
        Vrow[vb + 16] = f2bf(v1);
        Vrow[vb + 32] = f2bf(v2);
        Vrow[vb + 48] = f2bf(v3);
      }
    }
}

// ---------------- fused aux gemm ----------------
__global__ __launch_bounds__(256) void k_gaux(
    const unsigned short* __restrict__ Acm, const unsigned short* __restrict__ Bcm,
    const float* __restrict__ bqa, const float* __restrict__ bka,
    const float* __restrict__ wa,
    unsigned short* __restrict__ qcf, unsigned short* __restrict__ kcf)
{
  const int M = 8192, N = 512, K = 256;
  const int bm = blockIdx.y * 128, bn = blockIdx.x * 128;
  const int tid = threadIdx.x, lane = tid & 63, wv = tid >> 6;
  const int wr = wv >> 1, wc = wv & 1;
  const int lrow = lane & 15, lgrp = lane >> 4;
  fx4 acc[4][4];
#pragma unroll
  for (int m = 0; m < 4; ++m)
#pragma unroll
    for (int n = 0; n < 4; ++n) acc[m][n] = (fx4){0.f, 0.f, 0.f, 0.f};
  for (int k0 = 0; k0 < K; k0 += 32) {
    bh8 af[4], bf[4];
#pragma unroll
    for (int m = 0; m < 4; ++m)
      af[m] = *(const bh8*)(Acm + (((size_t)((k0 >> 3) + lgrp)) * M + bm + wr * 64 + m * 16 + lrow) * 8);
#pragma unroll
    for (int n = 0; n < 4; ++n)
      bf[n] = *(const bh8*)(Bcm + (((size_t)((k0 >> 3) + lgrp)) * N + bn + wc * 64 + n * 16 + lrow) * 8);
#pragma unroll
    for (int m = 0; m < 4; ++m)
#pragma unroll
      for (int n = 0; n < 4; ++n)
        acc[m][n] = __builtin_amdgcn_mfma_f32_16x16x32_bf16(af[m], bf[n], acc[m][n], 0, 0, 0);
  }
  const int isK = (bn >> 8) & 1;
  const int hh0 = (((bn & 255) + wc * 64) >> 5) & 7;
  const float wa0 = wa[0];
  const float* bias = isK ? bka : bqa;
  float bvals[4];
#pragma unroll
  for (int n = 0; n < 4; ++n) bvals[n] = bias[(hh0 + (n >> 1)) * 32 + (n & 1) * 16 + lrow];
  unsigned short* dst = isK ? kcf : qcf;
  const float scale = isK ? 1.0f : wa0;
#pragma unroll
  for (int m = 0; m < 4; ++m)
#pragma unroll
    for (int r = 0; r < 4; ++r) {
      int row = bm + wr * 64 + m * 16 + lgrp * 4 + r;
      int b = row >> 10, t = row & 1023;
      float v0 = acc[m][0][r] + bvals[0];
      float v1 = acc[m][1][r] + bvals[1];
      float v2 = acc[m][2][r] + bvals[2];
      float v3 = acc[m][3][r] + bvals[3];
      float plo = v0 * v0 + v1 * v1;
      float phi = v2 * v2 + v3 * v3;
      plo += __shfl_xor(plo, 1); plo += __shfl_xor(plo, 2);
      plo += __shfl_xor(plo, 4); plo += __shfl_xor(plo, 8);
      phi += __shfl_xor(phi, 1); phi += __shfl_xor(phi, 2);
      phi += __shfl_xor(phi, 4); phi += __shfl_xor(phi, 8);
      float rlo = scale / fmaxf(sqrtf(plo), 1e-12f);
      float rhi = scale / fmaxf(sqrtf(phi), 1e-12f);
      size_t b0 = (size_t)(b * 8 + hh0) * 65536 + (size_t)(lrow >> 3) * 8192 + (size_t)t * 8 + (lrow & 7);
      size_t b1 = (size_t)(b * 8 + hh0 + 1) * 65536 + (size_t)(lrow >> 3) * 8192 + (size_t)t * 8 + (lrow & 7);
      dst[b0 + 0]     = f2bf(v0 * rlo);
      dst[b0 + 16384] = f2bf(v1 * rlo);
      dst[b1 + 0]     = f2bf(v2 * rhi);
      dst[b1 + 16384] = f2bf(v3 * rhi);
    }
}

// ---------------- fused pos gemm ----------------
__global__ __launch_bounds__(256) void k_gpos(
    const unsigned short* __restrict__ Acm, const unsigned short* __restrict__ Bcm,
    const float* __restrict__ bqp, const float* __restrict__ bkp,
    const float* __restrict__ wp,
    unsigned short* __restrict__ qcf, unsigned short* __restrict__ kcf)
{
  const int M = 8192, N = 256, K = 128;
  const int bm = blockIdx.y * 128, bn = blockIdx.x * 128;
  const int tid = threadIdx.x, lane = tid & 63, wv = tid >> 6;
  const int wr = wv >> 1, wc = wv & 1;
  const int lrow = lane & 15, lgrp = lane >> 4;
  fx4 acc[4][4];
#pragma unroll
  for (int m = 0; m < 4; ++m)
#pragma unroll
    for (int n = 0; n < 4; ++n) acc[m][n] = (fx4){0.f, 0.f, 0.f, 0.f};
  for (int k0 = 0; k0 < K; k0 += 32) {
    bh8 af[4], bf[4];
#pragma unroll
    for (int m = 0; m < 4; ++m)
      af[m] = *(const bh8*)(Acm + (((size_t)((k0 >> 3) + lgrp)) * M + bm + wr * 64 + m * 16 + lrow) * 8);
#pragma unroll
    for (int n = 0; n < 4; ++n)
      bf[n] = *(const bh8*)(Bcm + (((size_t)((k0 >> 3) + lgrp)) * N + bn + wc * 64 + n * 16 + lrow) * 8);
#pragma unroll
    for (int m = 0; m < 4; ++m)
#pragma unroll
      for (int n = 0; n < 4; ++n)
        acc[m][n] = __builtin_amdgcn_mfma_f32_16x16x32_bf16(af[m], bf[n], acc[m][n], 0, 0, 0);
  }
  const int isK = (bn >> 7) & 1;
  const int bh0 = (((bn & 127) + wc * 64) >> 4) & 7;
  const float wp0 = wp[0];
  const float* bias = isK ? bkp : bqp;
  float bvals[4];
#pragma unroll
  for (int n = 0; n < 4; ++n) bvals[n] = bias[(bh0 + n) * 16 + lrow];
  unsigned short* dst = isK ? kcf : qcf;
  const float scale = isK ? 1.0f : wp0;
#pragma unroll
  for (int m = 0; m < 4; ++m)
#pragma unroll
    for (int r = 0; r < 4; ++r) {
      int row = bm + wr * 64 + m * 16 + lgrp * 4 + r;
      int b = row >> 10, t = row & 1023;
      float v[4];
      v[0] = acc[m][0][r] + bvals[0];
      v[1] = acc[m][1][r] + bvals[1];
      v[2] = acc[m][2][r] + bvals[2];
      v[3] = acc[m][3][r] + bvals[3];
#pragma unroll
      for (int n = 0; n < 4; ++n) {
        float p = v[n] * v[n];
        p += __shfl_xor(p, 1); p += __shfl_xor(p, 2);
        p += __shfl_xor(p, 4); p += __shfl_xor(p, 8);
        float rn = scale / fmaxf(sqrtf(p), 1e-12f);
        size_t addr = (size_t)(b * 8 + bh0 + n) * 65536 + (size_t)(4 + (lrow >> 3)) * 8192
                    + (size_t)t * 8 + (lrow & 7);
        dst[addr] = f2bf(v[n] * rn);
      }
    }
}

// ---------------- V transpose ----------------
__global__ __launch_bounds__(256) void k_vtr(
    const unsigned short* __restrict__ Vrow, unsigned short* __restrict__ Vc)
{
  __shared__ unsigned short tile[64][72];
  const int tt = blockIdx.x, bh = blockIdx.y;
  const int tid = threadIdx.x;
  const int r = tid & 63, g = tid >> 6;
  const unsigned short* src = Vrow + ((size_t)bh * NT + tt * 64 + r) * 64 + g * 16;
  int4 v0 = *(const int4*)(src);
  int4 v1 = *(const int4*)(src + 8);
  const unsigned short* pv0 = (const unsigned short*)&v0;
  const unsigned short* pv1 = (const unsigned short*)&v1;
#pragma unroll
  for (int j = 0; j < 8; ++j) tile[g * 16 + j][r] = pv0[j];
#pragma unroll
  for (int j = 0; j < 8; ++j) tile[g * 16 + 8 + j][r] = pv1[j];
  __syncthreads();
  unsigned short* dst0 = Vc + ((size_t)(bh * 128 + tt * 8 + g * 2) * 64 + r) * 8;
  unsigned short* dst1 = Vc + ((size_t)(bh * 128 + tt * 8 + g * 2 + 1) * 64 + r) * 8;
  *(int4*)dst0 = *(const int4*)&tile[r][g * 16];
  *(int4*)(dst1) = *(const int4*)&tile[r][g * 16 + 8];
}

// ---------------- slide body (EDGE: full cnt; else cnt==17) ----------------
template<bool EDGE, bool PBM>
__device__ __forceinline__ void slide_body(
    const float (*Se)[81], const unsigned short (*Pd)[66],
    int a0, int c0, int b, int hh, int wv, int lane, int base_cl,
    float* lacc, float* __restrict__ attn, unsigned short* __restrict__ PB)
{
  float dval = 0.f;
  {
    int rr = wv * 16 + (lane & 15);
#pragma unroll
    for (int u = 0; u <= 16; ++u) dval += Se[rr + u][u];
  }
  float num = 0.f;
#pragma unroll
  for (int s = 0; s < 16; ++s) {
    int a_l = wv * 16 + s;
    int c_l = (base_cl + s) & 63;
    if (s == 0) {
      num = 0.f;
#pragma unroll
      for (int u = 0; u <= 16; ++u) num += Se[a_l + u][c_l + u];
    } else {
      int cm1 = (c_l == 0) ? 0 : (c_l - 1);
      float up = Se[a_l + 16][c_l + 16] - Se[a_l - 1][cm1];
      float dS = __shfl(dval, s);
      num = (c_l == 0) ? dS : (num + up);
    }
    int a = a0 + a_l, c = c0 + c_l;
    float sim;
    if (EDGE) {
      int mn = min(a, c), mx = max(a, c);
      float cntf = (float)(min(8, mn) + min(8, 1023 - mx) + 1);
      sim = num * __builtin_amdgcn_rcpf(cntf) + bf2f(Pd[a_l][c_l]);
    } else {
      sim = num * (1.0f / 17.0f) + bf2f(Pd[a_l][c_l]);
    }
    float pe = __expf(sim);
    lacc[s] += pe;
    size_t oidx = (((size_t)(b * NT + a)) * NH + hh) * NT + c;
    if (PBM) PB[oidx] = f2bf(pe);
    else     attn[oidx] = pe;
  }
}

// ---------------- sim kernel: ctg=2, XCD-swizzled, chunk-major frags ----------------
// grid 2048 flat. wgid = (flat&7)*256 + flat>>3. bh=wgid>>5, ctg=(wgid>>4)&1, at=wgid&15
// Double-buffered Se/Pd: ONE barrier per ct (was 2). Per iteration each wave issues
// se_pd(ct+1 -> buf^1) first (VMEM latency hides under slide), then slide(ct -> buf),
// then barrier. WAR safe by parity: buf[(i+1)&1] last read at slide(i-1), barrier-separated.
// LDS 68.7 KB -> 2 blocks/CU static == measured residency of the 34.8 KB version.
template<bool PBM>
__global__ __launch_bounds__(256) void k_sim(
    const unsigned short* __restrict__ Qf, const unsigned short* __restrict__ Kf,
    const unsigned short* __restrict__ qcf, const unsigned short* __restrict__ kcf,
    float* __restrict__ lsumP, float* __restrict__ attn, unsigned short* __restrict__ PB)
{
  __shared__ float Se[2][80][81];
  __shared__ unsigned short Pd[2][64][66];
  const int flat = blockIdx.x;
  const int wgid = (flat & 7) * 256 + (flat >> 3);
  const int bh = wgid >> 5;
  const int ctg = (wgid >> 4) & 1;
  const int at = wgid & 15;
  const int a0 = at * 64;
  const int b = bh >> 3, hh = bh & 7;
  const int tid = threadIdx.x;
  const int lane = tid & 63, wv = tid >> 6;
  const int lrow16 = lane & 15, lgrp = lane >> 4;
  const bh8 zfrag = {0, 0, 0, 0, 0, 0, 0, 0};
  const int base_cl = (wv * 16 + lane) & 63;
  float lacc[16];
#pragma unroll
  for (int s = 0; s < 16; ++s) lacc[s] = 0.f;

  const unsigned short* Qc = Qf + (size_t)(bh * 8 + lgrp) * NT * 8;
  const unsigned short* Kc = Kf + (size_t)(bh * 8 + lgrp) * NT * 8;

  bh8 qa0, qa1;
  {
    const unsigned short* qb = qcf + ((size_t)(bh * 8 + lgrp) * NT + a0 + wv * 16 + lrow16) * 8;
    qa0 = *(const bh8*)(qb);
    qa1 = *(const bh8*)(qb + (size_t)4 * NT * 8);
  }

  auto se_pd = [&](int ct, int bufi) {
    const int c0 = ct * 64;
    // ---- Se: 25 ext tiles (16x16) over 4 waves ----
#pragma unroll
    for (int i = 0; i < 7; ++i) {
      int tt = wv + 4 * i;
      if (tt < 25) {
        int tr = tt / 5, tc = tt % 5;
        int ar = a0 - 8 + tr * 16 + lrow16;
        int kr = c0 - 8 + tc * 16 + lrow16;
        bool av = (unsigned)ar < (unsigned)NT;
        bool bv = (unsigned)kr < (unsigned)NT;
        const unsigned short* ap = Qc + (size_t)(av ? ar : 0) * 8;
        const unsigned short* bp = Kc + (size_t)(bv ? kr : 0) * 8;
        bh8 af0 = av ? *(const bh8*)(ap) : zfrag;
        bh8 af1 = av ? *(const bh8*)(ap + (size_t)4 * NT * 8) : zfrag;
        bh8 bf0 = bv ? *(const bh8*)(bp) : zfrag;
        bh8 bf1 = bv ? *(const bh8*)(bp + (size_t)4 * NT * 8) : zfrag;
        fx4 acc = {0.f, 0.f, 0.f, 0.f};
        acc = __builtin_amdgcn_mfma_f32_16x16x32_bf16(af0, bf0, acc, 0, 0, 0);
        acc = __builtin_amdgcn_mfma_f32_16x16x32_bf16(af1, bf1, acc, 0, 0, 0);
#pragma unroll
        for (int r = 0; r < 4; ++r)
          Se[bufi][tr * 16 + lgrp * 4 + r][tc * 16 + lrow16] = acc[r];
      }
    }
    // ---- Pd ----
#pragma unroll
    for (int n = 0; n < 4; ++n) {
      const unsigned short* kb = kcf + ((size_t)(bh * 8 + lgrp) * NT + c0 + n * 16 + lrow16) * 8;
      bh8 kb0 = *(const bh8*)(kb);
      bh8 kb1 = *(const bh8*)(kb + (size_t)4 * NT * 8);
      fx4 pacc = {0.f, 0.f, 0.f, 0.f};
      pacc = __builtin_amdgcn_mfma_f32_16x16x32_bf16(qa0, kb0, pacc, 0, 0, 0);
      pacc = __builtin_amdgcn_mfma_f32_16x16x32_bf16(qa1, kb1, pacc, 0, 0, 0);
#pragma unroll
      for (int r = 0; r < 4; ++r)
        Pd[bufi][wv * 16 + lgrp * 4 + r][n * 16 + lrow16] = f2bf(pacc[r]);
    }
  };

  se_pd(ctg * 8, 0);
  __syncthreads();

  for (int i = 0; i < 8; ++i) {
    const int ct = ctg * 8 + i;
    if (i < 7) se_pd(ct + 1, (i + 1) & 1);

    bool edge = (ct == 0) || (ct == 15) || (at == 0) || (at == 15);
    if (edge)
      slide_body<true, PBM>(Se[i & 1], Pd[i & 1], a0, ct * 64, b, hh, wv, lane, base_cl, lacc, attn, PB);
    else
      slide_body<false, PBM>(Se[i & 1], Pd[i & 1], a0, ct * 64, b, hh, wv, lane, base_cl, lacc, attn, PB);

    __syncthreads();
  }

#pragma unroll
  for (int s = 0; s < 16; ++s) {
    float v = lacc[s];
#pragma unroll
    for (int off = 32; off; off >>= 1) v += __shfl_xor(v, off);
    if (lane == 0)
      lsumP[(size_t)ctg * 65536 + (size_t)bh * NT + a0 + wv * 16 + s] = v;
  }
}

// ---------------- normalize attn + PV via MFMA ----------------
template<bool PBM>
__global__ __launch_bounds__(256) void k_pv(
    const unsigned short* __restrict__ Vc, const float* __restrict__ lsumP,
    float* __restrict__ attn, const unsigned short* __restrict__ PB,
    float* __restrict__ deta, unsigned short* __restrict__ detab)
{
  const int at = blockIdx.x, bh = blockIdx.y;
  const int a0 = at * 64;
  const int b = bh >> 3, hh = bh & 7;
  const int tid = threadIdx.x, lane = tid & 63, wv = tid >> 6;
  const int lrow = lane & 15, lgrp = lane >> 4;
  const int arow = a0 + wv * 16 + lrow;
  const size_t lidx = (size_t)bh * NT + arow;
  const float rl = 1.0f / (lsumP[lidx] + lsumP[65536 + lidx]);
  fx4 acc0 = {0.f,0.f,0.f,0.f}, acc1 = {0.f,0.f,0.f,0.f};
  fx4 acc2 = {0.f,0.f,0.f,0.f}, acc3 = {0.f,0.f,0.f,0.f};
  float* arowp = attn + (((size_t)(b * NT + arow)) * NH + hh) * NT;
  const unsigned short* pbrow = PBM ? (PB + (((size_t)(b * NT + arow)) * NH + hh) * NT) : nullptr;
  for (int ct = 0; ct < 16; ++ct) {
    const int c0 = ct * 64;
#pragma unroll
    for (int kh = 0; kh < 2; ++kh) {
      bh8 af;
      if (PBM) {
        af = *(const bh8*)(pbrow + c0 + kh * 32 + lgrp * 8);
        const unsigned short* ap = (const unsigned short*)&af;
        float4 o0, o1;
        o0.x = bf2f(ap[0]) * rl; o0.y = bf2f(ap[1]) * rl;
        o0.z = bf2f(ap[2]) * rl; o0.w = bf2f(ap[3]) * rl;
        o1.x = bf2f(ap[4]) * rl; o1.y = bf2f(ap[5]) * rl;
        o1.z = bf2f(ap[6]) * rl; o1.w = bf2f(ap[7]) * rl;
        *(float4*)(arowp + c0 + kh * 32 + lgrp * 8) = o0;
        *(float4*)(arowp + c0 + kh * 32 + lgrp * 8 + 4) = o1;
      } else {
        float* pp = arowp + c0 + kh * 32 + lgrp * 8;
        float4 p0 = *(float4*)pp;
        float4 p1 = *(float4*)(pp + 4);
        p0.x *= rl; p0.y *= rl; p0.z *= rl; p0.w *= rl;
        p1.x *= rl; p1.y *= rl; p1.z *= rl; p1.w *= rl;
        *(float4*)pp = p0;
        *(float4*)(pp + 4) = p1;
        unsigned short* afp = (unsigned short*)&af;
        afp[0] = f2bf(p0.x); afp[1] = f2bf(p0.y); afp[2] = f2bf(p0.z); afp[3] = f2bf(p0.w);
        afp[4] = f2bf(p1.x); afp[5] = f2bf(p1.y); afp[6] = f2bf(p1.z); afp[7] = f2bf(p1.w);
      }
      const unsigned short* vk = Vc + ((size_t)(bh * 128 + (c0 >> 3) + kh * 4 + lgrp) * 64 + lrow) * 8;
      acc0 = __builtin_amdgcn_mfma_f32_16x16x32_bf16(af, *(const bh8*)(vk + 0 * 16 * 8), acc0, 0, 0, 0);
      acc1 = __builtin_amdgcn_mfma_f32_16x16x32_bf16(af, *(const bh8*)(vk + 1 * 16 * 8), acc1, 0, 0, 0);
      acc2 = __builtin_amdgcn_mfma_f32_16x16x32_bf16(af, *(const bh8*)(vk + 2 * 16 * 8), acc2, 0, 0, 0);
      acc3 = __builtin_amdgcn_mfma_f32_16x16x32_bf16(af, *(const bh8*)(vk + 3 * 16 * 8), acc3, 0, 0, 0);
    }
  }
  const int orow = a0 + wv * 16 + lgrp * 4;
#pragma unroll
  for (int r = 0; r < 4; ++r) {
    float sc = 1.0f;
    if (PBM) {
      size_t li = (size_t)bh * NT + orow + r;
      sc = 1.0f / (lsumP[li] + lsumP[65536 + li]);
    }
    size_t rb = ((size_t)(b * NT + orow + r)) * DMODEL + hh * 64 + lrow;
    float d0 = acc0[r] * sc, d1 = acc1[r] * sc, d2 = acc2[r] * sc, d3 = acc3[r] * sc;
    deta[rb + 0]  = d0; detab[rb + 0]  = f2bf(d0);
    deta[rb + 16] = d1; detab[rb + 16] = f2bf(d1);
    deta[rb + 32] = d2; detab[rb + 32] = f2bf(d2);
    deta[rb + 48] = d3; detab[rb + 48] = f2bf(d3);
  }
}

// ---------------- final gemm ----------------
__global__ __launch_bounds__(256) void k_gout(
    const unsigned short* __restrict__ A, const unsigned short* __restrict__ B,
    float* __restrict__ C, int K, int N,
    const float* __restrict__ X, const float* __restrict__ bias)
{
  const int bm = blockIdx.y * 128, bn = blockIdx.x * 128;
  const int tid = threadIdx.x, lane = tid & 63, wv = tid >> 6;
  const int wr = wv >> 1, wc = wv & 1;
  const int lrow = lane & 15, lgrp = lane >> 4;
  fx4 acc[4][4];
#pragma unroll
  for (int m = 0; m < 4; ++m)
#pragma unroll
    for (int n = 0; n < 4; ++n) acc[m][n] = (fx4){0.f, 0.f, 0.f, 0.f};
  const unsigned short* Ab = A + (size_t)(bm + wr * 64 + lrow) * K + lgrp * 8;
  const unsigned short* Bb = B + (size_t)(bn + wc * 64 + lrow) * K + lgrp * 8;
  for (int k0 = 0; k0 < K; k0 += 32) {
    bh8 af[4], bf[4];
#pragma unroll
    for (int m = 0; m < 4; ++m) af[m] = *(const bh8*)(Ab + (size_t)m * 16 * K + k0);
#pragma unroll
    for (int n = 0; n < 4; ++n) bf[n] = *(const bh8*)(Bb + (size_t)n * 16 * K + k0);
#pragma unroll
    for (int m = 0; m < 4; ++m)
#pragma unroll
      for (int n = 0; n < 4; ++n)
        acc[m][n] = __builtin_amdgcn_mfma_f32_16x16x32_bf16(af[m], bf[n], acc[m][n], 0, 0, 0);
  }
#pragma unroll
  for (int m = 0; m < 4; ++m)
#pragma unroll
    for (int n = 0; n < 4; ++n)
#pragma unroll
      for (int r = 0; r < 4; ++r) {
        int row = bm + wr * 64 + m * 16 + lgrp * 4 + r;
        int col = bn + wc * 64 + n * 16 + lrow;
        C[(size_t)row * N + col] = acc[m][n][r] + X[(size_t)row * N + col] + bias[col];
      }
}

extern "C" void kernel_launch(void* const* d_in, const int* in_sizes, int n_in,
                              void* d_out, int out_size, void* d_ws, size_t ws_size,
                              hipStream_t stream) {
  const float* x   = (const float*)d_in[0];
  const float* aux = (const float*)d_in[1];
  const float* pos = (const float*)d_in[2];
  const float* Wq  = (const float*)d_in[3];
  const float* bq  = (const float*)d_in[4];
  const float* Wk  = (const float*)d_in[5];
  const float* bk  = (const float*)d_in[6];
  const float* Wv  = (const float*)d_in[7];
  const float* bv  = (const float*)d_in[8];
  const float* Wqa = (const float*)d_in[9];
  const float* bqa = (const float*)d_in[10];
  const float* Wka = (const float*)d_in[11];
  const float* bka = (const float*)d_in[12];
  const float* Wqp = (const float*)d_in[13];
  const float* bqp = (const float*)d_in[14];
  const float* Wkp = (const float*)d_in[15];
  const float* bkp = (const float*)d_in[16];
  const float* WO  = (const float*)d_in[17];
  const float* bO  = (const float*)d_in[18];
  const float* w   = (const float*)d_in[19];
  const float* wa  = (const float*)d_in[20];
  const float* wp  = (const float*)d_in[21];
  const int*   gdep = (const int*)d_in[22];

  float* out  = (float*)d_out;                        // [8,1024,512]
  float* attn = out + (size_t)4194304;                // [8,1024,8,1024]
  float* deta = out + (size_t)71303168;               // [8,1024,512]

  // cm activations live in the (not yet written) attn region
  unsigned short* xcm   = (unsigned short*)attn;              // [64][8192][8]
  unsigned short* auxcm = xcm + 4194304;                      // [32][8192][8]
  unsigned short* poscm = auxcm + 2097152;                    // [16][8192][8]

  // aliases: Qf -> out slot, Kf -> deta slot (both dead before overwrite)
  unsigned short* Qf = (unsigned short*)out;
  unsigned short* Kf = (unsigned short*)deta;

  float* ws = (float*)d_ws;
  float* lsumP = ws;                                        // 2*65536 f32
  unsigned short* Wqkvcm = (unsigned short*)(ws + 131072);  // 786432
  unsigned short* WO_mb  = Wqkvcm + 786432;                 // 262144
  unsigned short* Wacm   = WO_mb + 262144;                  // 131072
  unsigned short* Wpcm   = Wacm + 131072;                   // 32768
  unsigned short* Vrow   = Wpcm + 32768;                    // 4194304
  unsigned short* Vc     = Vrow + 4194304;                  // 4194304
  unsigned short* qcf    = Vc + 4194304;                    // 4194304
  unsigned short* kcf    = qcf + 4194304;                   // 4194304
  unsigned short* detab  = kcf + 4194304;                   // 4194304
  unsigned short* PB     = detab + 4194304;                 // 67108864 (if ws large)

  const size_t NEED_PB = 179109888ull;
  const bool pbm = (ws_size >= NEED_PB);

  k_prep<<<512, 256, 0, stream>>>(Wq, Wk, Wv, WO, gdep, Wqa, Wka, Wqp, Wkp,
                                  Wqkvcm, WO_mb, Wacm, Wpcm, qcf, kcf);
  k_tocm<<<dim3(128, 8), 256, 0, stream>>>(x, xcm, 8192, 512);
  k_tocm<<<dim3(128, 4), 256, 0, stream>>>(aux, auxcm, 8192, 256);
  k_tocm<<<dim3(128, 2), 256, 0, stream>>>(pos, poscm, 8192, 128);
  k_gqkv<<<dim3(12, 64), 256, 0, stream>>>(xcm, Wqkvcm, bq, bk, bv, w, Qf, Kf, Vrow);
  k_gaux<<<dim3(4, 64), 256, 0, stream>>>(auxcm, Wacm, bqa, bka, wa, qcf, kcf);
  k_gpos<<<dim3(2, 64), 256, 0, stream>>>(poscm, Wpcm, bqp, bkp, wp, qcf, kcf);
  k_vtr<<<dim3(16, 64), 256, 0, stream>>>(Vrow, Vc);
  if (pbm) {
    k_sim<true><<<2048, 256, 0, stream>>>(Qf, Kf, qcf, kcf, lsumP, attn, PB);
    k_pv<true><<<dim3(16, 64), 256, 0, stream>>>(Vc, lsumP, attn, PB, deta, detab);
  } else {
    k_sim<false><<<2048, 256, 0, stream>>>(Qf, Kf, qcf, kcf, lsumP, attn, PB);
    k_pv<false><<<dim3(16, 64), 256, 0, stream>>>(Vc, lsumP, attn, PB, deta, detab);
  }
  k_gout<<<dim3(4, 64), 256, 0, stream>>>(detab, WO_mb, out, 512, 512, x, bO);
}

// Round 14
// 392.796 us; speedup vs baseline: 1.4308x; 1.0261x over previous
//
#include <hip/hip_runtime.h>
#include <math.h>

#define NB 8
#define NH 8
#define NT 1024
#define DMODEL 512

typedef short bh8 __attribute__((ext_vector_type(8)));   // 8 bf16 (4 VGPRs)
typedef float fx4 __attribute__((ext_vector_type(4)));   // MFMA accumulator

__device__ __forceinline__ unsigned short f2bf(float f) {
  union { float f; unsigned int u; } v; v.f = f;
  unsigned int u = v.u + 0x7FFFu + ((v.u >> 16) & 1u);
  return (unsigned short)(u >> 16);
}
__device__ __forceinline__ float bf2f(unsigned short h) {
  union { unsigned int u; float f; } v; v.u = ((unsigned int)h) << 16;
  return v.f;
}

// ---------------- merged prep: weights mask+cm, pad chunks, activations -> chunk-major bf16 ----
// blocks [0,512): weight prep; [512,1536): x tocm; [1536,2048): aux tocm; [2048,2304): pos tocm
__global__ __launch_bounds__(256) void k_prep(
    const float* __restrict__ Wq, const float* __restrict__ Wk,
    const float* __restrict__ Wv, const float* __restrict__ WO,
    const int* __restrict__ g,
    const float* __restrict__ Wqa, const float* __restrict__ Wka,
    const float* __restrict__ Wqp, const float* __restrict__ Wkp,
    const float* __restrict__ x, const float* __restrict__ aux, const float* __restrict__ pos,
    unsigned short* __restrict__ Wqkvcm, unsigned short* __restrict__ WO_mb,
    unsigned short* __restrict__ Wacm, unsigned short* __restrict__ Wpcm,
    unsigned short* __restrict__ qcf, unsigned short* __restrict__ kcf,
    unsigned short* __restrict__ xcm, unsigned short* __restrict__ auxcm,
    unsigned short* __restrict__ poscm)
{
  __shared__ unsigned short t16[64][80];
  const int bid = blockIdx.x;
  const int tid = threadIdx.x;
  if (bid < 512) {
    int stride = 512 * 256;
    int tid0 = bid * 256 + tid;
    for (int i = tid0; i < 1536 * 512; i += stride) {
      int m = i & 511;
      int j = i >> 9;
      int k = j & 63;
      int hh = (j >> 6) & 7;
      int qkv = j >> 9;
      const float* W = (qkv == 0) ? Wq : (qkv == 1 ? Wk : Wv);
      float val = W[(hh * 64 + k) * 512 + m] * (float)g[k * 64 + (m & 63)];
      Wqkvcm[((size_t)(m >> 3) * 1536 + j) * 8 + (m & 7)] = f2bf(val);
    }
    for (int i = tid0; i < 512 * 512; i += stride) {
      int d = i & 511, e = i >> 9;
      WO_mb[i] = f2bf(WO[i] * (float)g[(e & 63) * 64 + (d & 63)]);
    }
    for (int i = tid0; i < 512 * 256; i += stride) {
      int a = i & 255, j = i >> 8;
      float val = (j < 256) ? Wqa[j * 256 + a] : Wka[(j - 256) * 256 + a];
      Wacm[((size_t)(a >> 3) * 512 + j) * 8 + (a & 7)] = f2bf(val);
    }
    for (int i = tid0; i < 256 * 128; i += stride) {
      int p = i & 127, j = i >> 7;
      float val = (j < 128) ? Wqp[j * 128 + p] : Wkp[(j - 128) * 128 + p];
      Wpcm[((size_t)(p >> 3) * 256 + j) * 8 + (p & 7)] = f2bf(val);
    }
    for (int i = tid0; i < 64 * 16384; i += stride) {
      int bh = i >> 14, rest = i & 16383;
      size_t addr = (size_t)(bh * 8 + 6) * 8192 + rest;
      qcf[addr] = 0; kcf[addr] = 0;
    }
    return;
  }
  // tocm: f32 [M=8192][K] -> bf16 chunk-major [K/8][8192][8]
  const float* src;
  unsigned short* dst;
  int K, local;
  if (bid < 1536)      { src = x;   dst = xcm;   K = 512; local = bid - 512; }
  else if (bid < 2048) { src = aux; dst = auxcm; K = 256; local = bid - 1536; }
  else                 { src = pos; dst = poscm; K = 128; local = bid - 2048; }
  const int bm = (local & 127) * 64, bk = (local >> 7) * 64;
  {
    int r = tid >> 2, q = tid & 3;
    const float* sp = src + (size_t)(bm + r) * K + bk + q * 16;
#pragma unroll
    for (int j = 0; j < 4; ++j) {
      float4 v = *(const float4*)(sp + j * 4);
      t16[r][q * 16 + j * 4 + 0] = f2bf(v.x);
      t16[r][q * 16 + j * 4 + 1] = f2bf(v.y);
      t16[r][q * 16 + j * 4 + 2] = f2bf(v.z);
      t16[r][q * 16 + j * 4 + 3] = f2bf(v.w);
    }
  }
  __syncthreads();
  {
    int cq = tid >> 5, rr = tid & 31;
#pragma unroll
    for (int h = 0; h < 2; ++h) {
      int r2 = rr + h * 32;
      unsigned short* dp = dst + ((size_t)((bk >> 3) + cq) * 8192 + bm + r2) * 8;
      *(int4*)dp = *(const int4*)&t16[r2][cq * 8];
    }
  }
}

// ---------------- fused QKV gemm ----------------
__global__ __launch_bounds__(256) void k_gqkv(
    const unsigned short* __restrict__ Acm, const unsigned short* __restrict__ Bcm,
    const float* __restrict__ bq, const float* __restrict__ bk, const float* __restrict__ bv,
    const float* __restrict__ w,
    unsigned short* __restrict__ Qf, unsigned short* __restrict__ Kf,
    unsigned short* __restrict__ Vrow)
{
  const int M = 8192, N = 1536, K = 512;
  const int bm = blockIdx.y * 128, bn = blockIdx.x * 128;
  const int tid = threadIdx.x, lane = tid & 63, wv = tid >> 6;
  const int wr = wv >> 1, wc = wv & 1;
  const int lrow = lane & 15, lgrp = lane >> 4;
  fx4 acc[4][4];
#pragma unroll
  for (int m = 0; m < 4; ++m)
#pragma unroll
    for (int n = 0; n < 4; ++n) acc[m][n] = (fx4){0.f, 0.f, 0.f, 0.f};
  for (int k0 = 0; k0 < K; k0 += 32) {
    bh8 af[4], bf[4];
#pragma unroll
    for (int m = 0; m < 4; ++m)
      af[m] = *(const bh8*)(Acm + (((size_t)((k0 >> 3) + lgrp)) * M + bm + wr * 64 + m * 16 + lrow) * 8);
#pragma unroll
    for (int n = 0; n < 4; ++n)
      bf[n] = *(const bh8*)(Bcm + (((size_t)((k0 >> 3) + lgrp)) * N + bn + wc * 64 + n * 16 + lrow) * 8);
#pragma unroll
    for (int m = 0; m < 4; ++m)
#pragma unroll
      for (int n = 0; n < 4; ++n)
        acc[m][n] = __builtin_amdgcn_mfma_f32_16x16x32_bf16(af[m], bf[n], acc[m][n], 0, 0, 0);
  }
  const int qkv = bn >> 9;
  const int hh = ((bn + wc * 64) >> 6) & 7;
  const float w0 = w[0];
  const float* bias = (qkv == 0) ? bq : (qkv == 1 ? bk : bv);
  float bvals[4];
#pragma unroll
  for (int n = 0; n < 4; ++n) bvals[n] = bias[hh * 64 + n * 16 + lrow];
#pragma unroll
  for (int m = 0; m < 4; ++m)
#pragma unroll
    for (int r = 0; r < 4; ++r) {
      int row = bm + wr * 64 + m * 16 + lgrp * 4 + r;
      int b = row >> 10, t = row & 1023;
      int bh = b * 8 + hh;
      float v0 = acc[m][0][r] + bvals[0];
      float v1 = acc[m][1][r] + bvals[1];
      float v2 = acc[m][2][r] + bvals[2];
      float v3 = acc[m][3][r] + bvals[3];
      if (qkv < 2) {
        float p = v0 * v0 + v1 * v1 + v2 * v2 + v3 * v3;
        p += __shfl_xor(p, 1); p += __shfl_xor(p, 2);
        p += __shfl_xor(p, 4); p += __shfl_xor(p, 8);
        float rn = 1.0f / fmaxf(sqrtf(p), 1e-12f);
        if (qkv == 0) rn *= w0;
        unsigned short* dst = (qkv == 0) ? Qf : Kf;
        size_t base = (size_t)bh * 65536 + (size_t)(lrow >> 3) * 8192 + (size_t)t * 8 + (lrow & 7);
        dst[base + 0 * 16384] = f2bf(v0 * rn);
        dst[base + 1 * 16384] = f2bf(v1 * rn);
        dst[base + 2 * 16384] = f2bf(v2 * rn);
        dst[base + 3 * 16384] = f2bf(v3 * rn);
      } else {
        size_t vb = ((size_t)bh * NT + t) * 64 + lrow;
        Vrow[vb + 0]  = f2bf(v0);
        Vrow[vb + 16] = f2bf(v1);
        Vrow[vb + 32] = f2bf(v2);
        Vrow[vb + 48] = f2bf(v3);
      }
    }
}

// ---------------- fused aux gemm ----------------
__global__ __launch_bounds__(256) void k_gaux(
    const unsigned short* __restrict__ Acm, const unsigned short* __restrict__ Bcm,
    const float* __restrict__ bqa, const float* __restrict__ bka,
    const float* __restrict__ wa,
    unsigned short* __restrict__ qcf, unsigned short* __restrict__ kcf)
{
  const int M = 8192, N = 512, K = 256;
  const int bm = blockIdx.y * 128, bn = blockIdx.x * 128;
  const int tid = threadIdx.x, lane = tid & 63, wv = tid >> 6;
  const int wr = wv >> 1, wc = wv & 1;
  const int lrow = lane & 15, lgrp = lane >> 4;
  fx4 acc[4][4];
#pragma unroll
  for (int m = 0; m < 4; ++m)
#pragma unroll
    for (int n = 0; n < 4; ++n) acc[m][n] = (fx4){0.f, 0.f, 0.f, 0.f};
  for (int k0 = 0; k0 < K; k0 += 32) {
    bh8 af[4], bf[4];
#pragma unroll
    for (int m = 0; m < 4; ++m)
      af[m] = *(const bh8*)(Acm + (((size_t)((k0 >> 3) + lgrp)) * M + bm + wr * 64 + m * 16 + lrow) * 8);
#pragma unroll
    for (int n = 0; n < 4; ++n)
      bf[n] = *(const bh8*)(Bcm + (((size_t)((k0 >> 3) + lgrp)) * N + bn + wc * 64 + n * 16 + lrow) * 8);
#pragma unroll
    for (int m = 0; m < 4; ++m)
#pragma unroll
      for (int n = 0; n < 4; ++n)
        acc[m][n] = __builtin_amdgcn_mfma_f32_16x16x32_bf16(af[m], bf[n], acc[m][n], 0, 0, 0);
  }
  const int isK = (bn >> 8) & 1;
  const int hh0 = (((bn & 255) + wc * 64) >> 5) & 7;
  const float wa0 = wa[0];
  const float* bias = isK ? bka : bqa;
  float bvals[4];
#pragma unroll
  for (int n = 0; n < 4; ++n) bvals[n] = bias[(hh0 + (n >> 1)) * 32 + (n & 1) * 16 + lrow];
  unsigned short* dst = isK ? kcf : qcf;
  const float scale = isK ? 1.0f : wa0;
#pragma unroll
  for (int m = 0; m < 4; ++m)
#pragma unroll
    for (int r = 0; r < 4; ++r) {
      int row = bm + wr * 64 + m * 16 + lgrp * 4 + r;
      int b = row >> 10, t = row & 1023;
      float v0 = acc[m][0][r] + bvals[0];
      float v1 = acc[m][1][r] + bvals[1];
      float v2 = acc[m][2][r] + bvals[2];
      float v3 = acc[m][3][r] + bvals[3];
      float plo = v0 * v0 + v1 * v1;
      float phi = v2 * v2 + v3 * v3;
      plo += __shfl_xor(plo, 1); plo += __shfl_xor(plo, 2);
      plo += __shfl_xor(plo, 4); plo += __shfl_xor(plo, 8);
      phi += __shfl_xor(phi, 1); phi += __shfl_xor(phi, 2);
      phi += __shfl_xor(phi, 4); phi += __shfl_xor(phi, 8);
      float rlo = scale / fmaxf(sqrtf(plo), 1e-12f);
      float rhi = scale / fmaxf(sqrtf(phi), 1e-12f);
      size_t b0 = (size_t)(b * 8 + hh0) * 65536 + (size_t)(lrow >> 3) * 8192 + (size_t)t * 8 + (lrow & 7);
      size_t b1 = (size_t)(b * 8 + hh0 + 1) * 65536 + (size_t)(lrow >> 3) * 8192 + (size_t)t * 8 + (lrow & 7);
      dst[b0 + 0]     = f2bf(v0 * rlo);
      dst[b0 + 16384] = f2bf(v1 * rlo);
      dst[b1 + 0]     = f2bf(v2 * rhi);
      dst[b1 + 16384] = f2bf(v3 * rhi);
    }
}

// ---------------- fused pos gemm ----------------
__global__ __launch_bounds__(256) void k_gpos(
    const unsigned short* __restrict__ Acm, const unsigned short* __restrict__ Bcm,
    const float* __restrict__ bqp, const float* __restrict__ bkp,
    const float* __restrict__ wp,
    unsigned short* __restrict__ qcf, unsigned short* __restrict__ kcf)
{
  const int M = 8192, N = 256, K = 128;
  const int bm = blockIdx.y * 128, bn = blockIdx.x * 128;
  const int tid = threadIdx.x, lane = tid & 63, wv = tid >> 6;
  const int wr = wv >> 1, wc = wv & 1;
  const int lrow = lane & 15, lgrp = lane >> 4;
  fx4 acc[4][4];
#pragma unroll
  for (int m = 0; m < 4; ++m)
#pragma unroll
    for (int n = 0; n < 4; ++n) acc[m][n] = (fx4){0.f, 0.f, 0.f, 0.f};
  for (int k0 = 0; k0 < K; k0 += 32) {
    bh8 af[4], bf[4];
#pragma unroll
    for (int m = 0; m < 4; ++m)
      af[m] = *(const bh8*)(Acm + (((size_t)((k0 >> 3) + lgrp)) * M + bm + wr * 64 + m * 16 + lrow) * 8);
#pragma unroll
    for (int n = 0; n < 4; ++n)
      bf[n] = *(const bh8*)(Bcm + (((size_t)((k0 >> 3) + lgrp)) * N + bn + wc * 64 + n * 16 + lrow) * 8);
#pragma unroll
    for (int m = 0; m < 4; ++m)
#pragma unroll
      for (int n = 0; n < 4; ++n)
        acc[m][n] = __builtin_amdgcn_mfma_f32_16x16x32_bf16(af[m], bf[n], acc[m][n], 0, 0, 0);
  }
  const int isK = (bn >> 7) & 1;
  const int bh0 = (((bn & 127) + wc * 64) >> 4) & 7;
  const float wp0 = wp[0];
  const float* bias = isK ? bkp : bqp;
  float bvals[4];
#pragma unroll
  for (int n = 0; n < 4; ++n) bvals[n] = bias[(bh0 + n) * 16 + lrow];
  unsigned short* dst = isK ? kcf : qcf;
  const float scale = isK ? 1.0f : wp0;
#pragma unroll
  for (int m = 0; m < 4; ++m)
#pragma unroll
    for (int r = 0; r < 4; ++r) {
      int row = bm + wr * 64 + m * 16 + lgrp * 4 + r;
      int b = row >> 10, t = row & 1023;
      float v[4];
      v[0] = acc[m][0][r] + bvals[0];
      v[1] = acc[m][1][r] + bvals[1];
      v[2] = acc[m][2][r] + bvals[2];
      v[3] = acc[m][3][r] + bvals[3];
#pragma unroll
      for (int n = 0; n < 4; ++n) {
        float p = v[n] * v[n];
        p += __shfl_xor(p, 1); p += __shfl_xor(p, 2);
        p += __shfl_xor(p, 4); p += __shfl_xor(p, 8);
        float rn = scale / fmaxf(sqrtf(p), 1e-12f);
        size_t addr = (size_t)(b * 8 + bh0 + n) * 65536 + (size_t)(4 + (lrow >> 3)) * 8192
                    + (size_t)t * 8 + (lrow & 7);
        dst[addr] = f2bf(v[n] * rn);
      }
    }
}

// ---------------- V transpose ----------------
__global__ __launch_bounds__(256) void k_vtr(
    const unsigned short* __restrict__ Vrow, unsigned short* __restrict__ Vc)
{
  __shared__ unsigned short tile[64][72];
  const int tt = blockIdx.x, bh = blockIdx.y;
  const int tid = threadIdx.x;
  const int r = tid & 63, g = tid >> 6;
  const unsigned short* src = Vrow + ((size_t)bh * NT + tt * 64 + r) * 64 + g * 16;
  int4 v0 = *(const int4*)(src);
  int4 v1 = *(const int4*)(src + 8);
  const unsigned short* pv0 = (const unsigned short*)&v0;
  const unsigned short* pv1 = (const unsigned short*)&v1;
#pragma unroll
  for (int j = 0; j < 8; ++j) tile[g * 16 + j][r] = pv0[j];
#pragma unroll
  for (int j = 0; j < 8; ++j) tile[g * 16 + 8 + j][r] = pv1[j];
  __syncthreads();
  unsigned short* dst0 = Vc + ((size_t)(bh * 128 + tt * 8 + g * 2) * 64 + r) * 8;
  unsigned short* dst1 = Vc + ((size_t)(bh * 128 + tt * 8 + g * 2 + 1) * 64 + r) * 8;
  *(int4*)dst0 = *(const int4*)&tile[r][g * 16];
  *(int4*)(dst1) = *(const int4*)&tile[r][g * 16 + 8];
}

// ---------------- slide body (EDGE: full cnt; else cnt==17) ----------------
// dval: distributed reads (row=lane&15, ug=lane>>4 covers u=ug..16 step 4) + xor-reduce,
// replacing 17 replicated LDS reads per lane with <=5 + 2 shuffles.
template<bool EDGE, bool PBM>
__device__ __forceinline__ void slide_body(
    const float (*Se)[81], const unsigned short (*Pd)[66],
    int a0, int c0, int b, int hh, int wv, int lane, int base_cl,
    float* lacc, float* __restrict__ attn, unsigned short* __restrict__ PB)
{
  float dval;
  {
    int row = wv * 16 + (lane & 15);
    int ug = lane >> 4;
    float part = Se[row + ug][ug] + Se[row + ug + 4][ug + 4]
               + Se[row + ug + 8][ug + 8] + Se[row + ug + 12][ug + 12];
    if (ug == 0) part += Se[row + 16][16];
    part += __shfl_xor(part, 16);
    part += __shfl_xor(part, 32);
    dval = part;   // all lanes hold full sum for row (lane&15)
  }
  float num = 0.f;
#pragma unroll
  for (int s = 0; s < 16; ++s) {
    int a_l = wv * 16 + s;
    int c_l = (base_cl + s) & 63;
    if (s == 0) {
      num = 0.f;
#pragma unroll
      for (int u = 0; u <= 16; ++u) num += Se[a_l + u][c_l + u];
    } else {
      int cm1 = (c_l == 0) ? 0 : (c_l - 1);
      float up = Se[a_l + 16][c_l + 16] - Se[a_l - 1][cm1];
      float dS = __shfl(dval, s);
      num = (c_l == 0) ? dS : (num + up);
    }
    int a = a0 + a_l, c = c0 + c_l;
    float sim;
    if (EDGE) {
      int mn = min(a, c), mx = max(a, c);
      float cntf = (float)(min(8, mn) + min(8, 1023 - mx) + 1);
      sim = num * __builtin_amdgcn_rcpf(cntf) + bf2f(Pd[a_l][c_l]);
    } else {
      sim = num * (1.0f / 17.0f) + bf2f(Pd[a_l][c_l]);
    }
    float pe = __expf(sim);
    lacc[s] += pe;
    size_t oidx = (((size_t)(b * NT + a)) * NH + hh) * NT + c;
    if (PBM) PB[oidx] = f2bf(pe);
    else     attn[oidx] = pe;
  }
}

// ---------------- sim kernel: ctg=2, XCD-swizzled, chunk-major frags ----------------
// grid 2048 flat. wgid = (flat&7)*256 + flat>>3. bh=wgid>>5, ctg=(wgid>>4)&1, at=wgid&15
template<bool PBM>
__global__ __launch_bounds__(256) void k_sim(
    const unsigned short* __restrict__ Qf, const unsigned short* __restrict__ Kf,
    const unsigned short* __restrict__ qcf, const unsigned short* __restrict__ kcf,
    float* __restrict__ lsumP, float* __restrict__ attn, unsigned short* __restrict__ PB)
{
  __shared__ float Se[80][81];
  __shared__ unsigned short Pd[64][66];
  const int flat = blockIdx.x;
  const int wgid = (flat & 7) * 256 + (flat >> 3);
  const int bh = wgid >> 5;
  const int ctg = (wgid >> 4) & 1;
  const int at = wgid & 15;
  const int a0 = at * 64;
  const int b = bh >> 3, hh = bh & 7;
  const int tid = threadIdx.x;
  const int lane = tid & 63, wv = tid >> 6;
  const int lrow16 = lane & 15, lgrp = lane >> 4;
  const bh8 zfrag = {0, 0, 0, 0, 0, 0, 0, 0};
  const int base_cl = (wv * 16 + lane) & 63;
  float lacc[16];
#pragma unroll
  for (int s = 0; s < 16; ++s) lacc[s] = 0.f;

  const unsigned short* Qc = Qf + (size_t)(bh * 8 + lgrp) * NT * 8;
  const unsigned short* Kc = Kf + (size_t)(bh * 8 + lgrp) * NT * 8;

  bh8 qa0, qa1;
  {
    const unsigned short* qb = qcf + ((size_t)(bh * 8 + lgrp) * NT + a0 + wv * 16 + lrow16) * 8;
    qa0 = *(const bh8*)(qb);
    qa1 = *(const bh8*)(qb + (size_t)4 * NT * 8);
  }

  for (int ct = ctg * 8; ct < ctg * 8 + 8; ++ct) {
    const int c0 = ct * 64;
    __syncthreads();

#pragma unroll
    for (int i = 0; i < 7; ++i) {
      int tt = wv + 4 * i;
      if (tt < 25) {
        int tr = tt / 5, tc = tt % 5;
        int ar = a0 - 8 + tr * 16 + lrow16;
        int kr = c0 - 8 + tc * 16 + lrow16;
        bool av = (unsigned)ar < (unsigned)NT;
        bool bv = (unsigned)kr < (unsigned)NT;
        const unsigned short* ap = Qc + (size_t)(av ? ar : 0) * 8;
        const unsigned short* bp = Kc + (size_t)(bv ? kr : 0) * 8;
        bh8 af0 = av ? *(const bh8*)(ap) : zfrag;
        bh8 af1 = av ? *(const bh8*)(ap + (size_t)4 * NT * 8) : zfrag;
        bh8 bf0 = bv ? *(const bh8*)(bp) : zfrag;
        bh8 bf1 = bv ? *(const bh8*)(bp + (size_t)4 * NT * 8) : zfrag;
        fx4 acc = {0.f, 0.f, 0.f, 0.f};
        acc = __builtin_amdgcn_mfma_f32_16x16x32_bf16(af0, bf0, acc, 0, 0, 0);
        acc = __builtin_amdgcn_mfma_f32_16x16x32_bf16(af1, bf1, acc, 0, 0, 0);
#pragma unroll
        for (int r = 0; r < 4; ++r)
          Se[tr * 16 + lgrp * 4 + r][tc * 16 + lrow16] = acc[r];
      }
    }

#pragma unroll
    for (int n = 0; n < 4; ++n) {
      const unsigned short* kb = kcf + ((size_t)(bh * 8 + lgrp) * NT + c0 + n * 16 + lrow16) * 8;
      bh8 kb0 = *(const bh8*)(kb);
      bh8 kb1 = *(const bh8*)(kb + (size_t)4 * NT * 8);
      fx4 pacc = {0.f, 0.f, 0.f, 0.f};
      pacc = __builtin_amdgcn_mfma_f32_16x16x32_bf16(qa0, kb0, pacc, 0, 0, 0);
      pacc = __builtin_amdgcn_mfma_f32_16x16x32_bf16(qa1, kb1, pacc, 0, 0, 0);
#pragma unroll
      for (int r = 0; r < 4; ++r)
        Pd[wv * 16 + lgrp * 4 + r][n * 16 + lrow16] = f2bf(pacc[r]);
    }

    __syncthreads();

    bool edge = (ct == 0) || (ct == 15) || (at == 0) || (at == 15);
    if (edge)
      slide_body<true, PBM>(Se, Pd, a0, c0, b, hh, wv, lane, base_cl, lacc, attn, PB);
    else
      slide_body<false, PBM>(Se, Pd, a0, c0, b, hh, wv, lane, base_cl, lacc, attn, PB);
  }

#pragma unroll
  for (int s = 0; s < 16; ++s) {
    float v = lacc[s];
#pragma unroll
    for (int off = 32; off; off >>= 1) v += __shfl_xor(v, off);
    if (lane == 0)
      lsumP[(size_t)ctg * 65536 + (size_t)bh * NT + a0 + wv * 16 + s] = v;
  }
}

// ---------------- normalize attn + PV via MFMA ----------------
template<bool PBM>
__global__ __launch_bounds__(256) void k_pv(
    const unsigned short* __restrict__ Vc, const float* __restrict__ lsumP,
    float* __restrict__ attn, const unsigned short* __restrict__ PB,
    float* __restrict__ deta, unsigned short* __restrict__ detab)
{
  const int at = blockIdx.x, bh = blockIdx.y;
  const int a0 = at * 64;
  const int b = bh >> 3, hh = bh & 7;
  const int tid = threadIdx.x, lane = tid & 63, wv = tid >> 6;
  const int lrow = lane & 15, lgrp = lane >> 4;
  const int arow = a0 + wv * 16 + lrow;
  const size_t lidx = (size_t)bh * NT + arow;
  const float rl = 1.0f / (lsumP[lidx] + lsumP[65536 + lidx]);
  fx4 acc0 = {0.f,0.f,0.f,0.f}, acc1 = {0.f,0.f,0.f,0.f};
  fx4 acc2 = {0.f,0.f,0.f,0.f}, acc3 = {0.f,0.f,0.f,0.f};
  float* arowp = attn + (((size_t)(b * NT + arow)) * NH + hh) * NT;
  const unsigned short* pbrow = PBM ? (PB + (((size_t)(b * NT + arow)) * NH + hh) * NT) : nullptr;
  for (int ct = 0; ct < 16; ++ct) {
    const int c0 = ct * 64;
#pragma unroll
    for (int kh = 0; kh < 2; ++kh) {
      bh8 af;
      if (PBM) {
        af = *(const bh8*)(pbrow + c0 + kh * 32 + lgrp * 8);
        const unsigned short* ap = (const unsigned short*)&af;
        float4 o0, o1;
        o0.x = bf2f(ap[0]) * rl; o0.y = bf2f(ap[1]) * rl;
        o0.z = bf2f(ap[2]) * rl; o0.w = bf2f(ap[3]) * rl;
        o1.x = bf2f(ap[4]) * rl; o1.y = bf2f(ap[5]) * rl;
        o1.z = bf2f(ap[6]) * rl; o1.w = bf2f(ap[7]) * rl;
        *(float4*)(arowp + c0 + kh * 32 + lgrp * 8) = o0;
        *(float4*)(arowp + c0 + kh * 32 + lgrp * 8 + 4) = o1;
      } else {
        float* pp = arowp + c0 + kh * 32 + lgrp * 8;
        float4 p0 = *(float4*)pp;
        float4 p1 = *(float4*)(pp + 4);
        p0.x *= rl; p0.y *= rl; p0.z *= rl; p0.w *= rl;
        p1.x *= rl; p1.y *= rl; p1.z *= rl; p1.w *= rl;
        *(float4*)pp = p0;
        *(float4*)(pp + 4) = p1;
        unsigned short* afp = (unsigned short*)&af;
        afp[0] = f2bf(p0.x); afp[1] = f2bf(p0.y); afp[2] = f2bf(p0.z); afp[3] = f2bf(p0.w);
        afp[4] = f2bf(p1.x); afp[5] = f2bf(p1.y); afp[6] = f2bf(p1.z); afp[7] = f2bf(p1.w);
      }
      const unsigned short* vk = Vc + ((size_t)(bh * 128 + (c0 >> 3) + kh * 4 + lgrp) * 64 + lrow) * 8;
      acc0 = __builtin_amdgcn_mfma_f32_16x16x32_bf16(af, *(const bh8*)(vk + 0 * 16 * 8), acc0, 0, 0, 0);
      acc1 = __builtin_amdgcn_mfma_f32_16x16x32_bf16(af, *(const bh8*)(vk + 1 * 16 * 8), acc1, 0, 0, 0);
      acc2 = __builtin_amdgcn_mfma_f32_16x16x32_bf16(af, *(const bh8*)(vk + 2 * 16 * 8), acc2, 0, 0, 0);
      acc3 = __builtin_amdgcn_mfma_f32_16x16x32_bf16(af, *(const bh8*)(vk + 3 * 16 * 8), acc3, 0, 0, 0);
    }
  }
  const int orow = a0 + wv * 16 + lgrp * 4;
#pragma unroll
  for (int r = 0; r < 4; ++r) {
    float sc = 1.0f;
    if (PBM) {
      size_t li = (size_t)bh * NT + orow + r;
      sc = 1.0f / (lsumP[li] + lsumP[65536 + li]);
    }
    size_t rb = ((size_t)(b * NT + orow + r)) * DMODEL + hh * 64 + lrow;
    float d0 = acc0[r] * sc, d1 = acc1[r] * sc, d2 = acc2[r] * sc, d3 = acc3[r] * sc;
    deta[rb + 0]  = d0; detab[rb + 0]  = f2bf(d0);
    deta[rb + 16] = d1; detab[rb + 16] = f2bf(d1);
    deta[rb + 32] = d2; detab[rb + 32] = f2bf(d2);
    deta[rb + 48] = d3; detab[rb + 48] = f2bf(d3);
  }
}

// ---------------- final gemm ----------------
__global__ __launch_bounds__(256) void k_gout(
    const unsigned short* __restrict__ A, const unsigned short* __restrict__ B,
    float* __restrict__ C, int K, int N,
    const float* __restrict__ X, const float* __restrict__ bias)
{
  const int bm = blockIdx.y * 128, bn = blockIdx.x * 128;
  const int tid = threadIdx.x, lane = tid & 63, wv = tid >> 6;
  const int wr = wv >> 1, wc = wv & 1;
  const int lrow = lane & 15, lgrp = lane >> 4;
  fx4 acc[4][4];
#pragma unroll
  for (int m = 0; m < 4; ++m)
#pragma unroll
    for (int n = 0; n < 4; ++n) acc[m][n] = (fx4){0.f, 0.f, 0.f, 0.f};
  const unsigned short* Ab = A + (size_t)(bm + wr * 64 + lrow) * K + lgrp * 8;
  const unsigned short* Bb = B + (size_t)(bn + wc * 64 + lrow) * K + lgrp * 8;
  for (int k0 = 0; k0 < K; k0 += 32) {
    bh8 af[4], bf[4];
#pragma unroll
    for (int m = 0; m < 4; ++m) af[m] = *(const bh8*)(Ab + (size_t)m * 16 * K + k0);
#pragma unroll
    for (int n = 0; n < 4; ++n) bf[n] = *(const bh8*)(Bb + (size_t)n * 16 * K + k0);
#pragma unroll
    for (int m = 0; m < 4; ++m)
#pragma unroll
      for (int n = 0; n < 4; ++n)
        acc[m][n] = __builtin_amdgcn_mfma_f32_16x16x32_bf16(af[m], bf[n], acc[m][n], 0, 0, 0);
  }
#pragma unroll
  for (int m = 0; m < 4; ++m)
#pragma unroll
    for (int n = 0; n < 4; ++n)
#pragma unroll
      for (int r = 0; r < 4; ++r) {
        int row = bm + wr * 64 + m * 16 + lgrp * 4 + r;
        int col = bn + wc * 64 + n * 16 + lrow;
        C[(size_t)row * N + col] = acc[m][n][r] + X[(size_t)row * N + col] + bias[col];
      }
}

extern "C" void kernel_launch(void* const* d_in, const int* in_sizes, int n_in,
                              void* d_out, int out_size, void* d_ws, size_t ws_size,
                              hipStream_t stream) {
  const float* x   = (const float*)d_in[0];
  const float* aux = (const float*)d_in[1];
  const float* pos = (const float*)d_in[2];
  const float* Wq  = (const float*)d_in[3];
  const float* bq  = (const float*)d_in[4];
  const float* Wk  = (const float*)d_in[5];
  const float* bk  = (const float*)d_in[6];
  const float* Wv  = (const float*)d_in[7];
  const float* bv  = (const float*)d_in[8];
  const float* Wqa = (const float*)d_in[9];
  const float* bqa = (const float*)d_in[10];
  const float* Wka = (const float*)d_in[11];
  const float* bka = (const float*)d_in[12];
  const float* Wqp = (const float*)d_in[13];
  const float* bqp = (const float*)d_in[14];
  const float* Wkp = (const float*)d_in[15];
  const float* bkp = (const float*)d_in[16];
  const float* WO  = (const float*)d_in[17];
  const float* bO  = (const float*)d_in[18];
  const float* w   = (const float*)d_in[19];
  const float* wa  = (const float*)d_in[20];
  const float* wp  = (const float*)d_in[21];
  const int*   gdep = (const int*)d_in[22];

  float* out  = (float*)d_out;                        // [8,1024,512]
  float* attn = out + (size_t)4194304;                // [8,1024,8,1024]
  float* deta = out + (size_t)71303168;               // [8,1024,512]

  // cm activations live in the (not yet written) attn region
  unsigned short* xcm   = (unsigned short*)attn;              // [64][8192][8]
  unsigned short* auxcm = xcm + 4194304;                      // [32][8192][8]
  unsigned short* poscm = auxcm + 2097152;                    // [16][8192][8]

  // aliases: Qf -> out slot, Kf -> deta slot (both dead before overwrite)
  unsigned short* Qf = (unsigned short*)out;
  unsigned short* Kf = (unsigned short*)deta;

  float* ws = (float*)d_ws;
  float* lsumP = ws;                                        // 2*65536 f32
  unsigned short* Wqkvcm = (unsigned short*)(ws + 131072);  // 786432
  unsigned short* WO_mb  = Wqkvcm + 786432;                 // 262144
  unsigned short* Wacm   = WO_mb + 262144;                  // 131072
  unsigned short* Wpcm   = Wacm + 131072;                   // 32768
  unsigned short* Vrow   = Wpcm + 32768;                    // 4194304
  unsigned short* Vc     = Vrow + 4194304;                  // 4194304
  unsigned short* qcf    = Vc + 4194304;                    // 4194304
  unsigned short* kcf    = qcf + 4194304;                   // 4194304
  unsigned short* detab  = kcf + 4194304;                   // 4194304
  unsigned short* PB     = detab + 4194304;                 // 67108864 (if ws large)

  const size_t NEED_PB = 179109888ull;
  const bool pbm = (ws_size >= NEED_PB);

  k_prep<<<2304, 256, 0, stream>>>(Wq, Wk, Wv, WO, gdep, Wqa, Wka, Wqp, Wkp,
                                   x, aux, pos,
                                   Wqkvcm, WO_mb, Wacm, Wpcm, qcf, kcf,
                                   xcm, auxcm, poscm);
  k_gqkv<<<dim3(12, 64), 256, 0, stream>>>(xcm, Wqkvcm, bq, bk, bv, w, Qf, Kf, Vrow);
  k_gaux<<<dim3(4, 64), 256, 0, stream>>>(auxcm, Wacm, bqa, bka, wa, qcf, kcf);
  k_gpos<<<dim3(2, 64), 256, 0, stream>>>(poscm, Wpcm, bqp, bkp, wp, qcf, kcf);
  k_vtr<<<dim3(16, 64), 256, 0, stream>>>(Vrow, Vc);
  if (pbm) {
    k_sim<true><<<2048, 256, 0, stream>>>(Qf, Kf, qcf, kcf, lsumP, attn, PB);
    k_pv<true><<<dim3(16, 64), 256, 0, stream>>>(Vc, lsumP, attn, PB, deta, detab);
  } else {
    k_sim<false><<<2048, 256, 0, stream>>>(Qf, Kf, qcf, kcf, lsumP, attn, PB);
    k_pv<false><<<dim3(16, 64), 256, 0, stream>>>(Vc, lsumP, attn, PB, deta, detab);
  }
  k_gout<<<dim3(4, 64), 256, 0, stream>>>(detab, WO_mb, out, 512, 512, x, bO);
}